// Round 1
// baseline (2081.537 us; speedup 1.0000x reference)
//
#include <hip/hip_runtime.h>
#include <hip/hip_bf16.h>

// RelationalTransformer forward on MI355X (gfx950).
// Strategy: bf16 MFMA for all GEMMs + flash attention; fp32 residual stream.
// Workspace layout (needs ~116 MiB):
//   [0,8M)    x        fp32 [4096,512] residual stream
//   [8M,12M)  h        bf16 normalized activations
//   [12..24M) q,k,v,o  bf16 [4096,512]
//   [28M,44M) fa       bf16 [4096,2048]
//   [44M,60M) fb       bf16 [4096,2048]
//   [60M,116M) bf16 weights (7 arrays x 8 MiB)

typedef __attribute__((ext_vector_type(4))) float f32x4;
typedef __attribute__((ext_vector_type(8))) short s16x8;
typedef __attribute__((ext_vector_type(4))) short s16x4;

#define SEQ 1024
#define DM 512
#define MTOT 4096
#define EPSV 1.1920929e-07f

static __device__ __forceinline__ float b2f(short s) {
  unsigned u = ((unsigned)(unsigned short)s) << 16;
  return __builtin_bit_cast(float, u);
}
static __device__ __forceinline__ short f2b(float f) {
  unsigned u = __builtin_bit_cast(unsigned, f);
  u = (u + 0x7fffu + ((u >> 16) & 1u)) >> 16;  // RNE; inputs never NaN
  return (short)(unsigned short)u;
}

#define MFMA_BF16(a, b, c) __builtin_amdgcn_mfma_f32_16x16x32_bf16((a), (b), (c), 0, 0, 0)
#define GLLDS(gp, lp)                                                                        \
  __builtin_amdgcn_global_load_lds((const __attribute__((address_space(1))) unsigned*)(gp),  \
                                   (__attribute__((address_space(3))) unsigned*)(lp), 16, 0, 0)

// ---------------- fp32 -> bf16 weight conversion ----------------
__global__ void cvt_kernel(const f32x4* __restrict__ src, s16x4* __restrict__ dst, int n4) {
  int i = blockIdx.x * 256 + threadIdx.x;
  if (i >= n4) return;
  f32x4 v = src[i];
  s16x4 o;
  o[0] = f2b(v[0]); o[1] = f2b(v[1]); o[2] = f2b(v[2]); o[3] = f2b(v[3]);
  dst[i] = o;
}

// ---------------- RMSNorm: one wave per row (512 elems, 8/lane) ----------------
template<bool F32OUT>
__global__ void rmsnorm_kernel(const float* __restrict__ x, const float* __restrict__ g,
                               void* __restrict__ outp) {
  int row = blockIdx.x * 4 + (threadIdx.x >> 6);
  int lane = threadIdx.x & 63;
  const float* xr = x + (size_t)row * DM + lane * 8;
  f32x4 a = *(const f32x4*)xr;
  f32x4 b = *(const f32x4*)(xr + 4);
  float ss = a[0]*a[0]+a[1]*a[1]+a[2]*a[2]+a[3]*a[3]+b[0]*b[0]+b[1]*b[1]+b[2]*b[2]+b[3]*b[3];
#pragma unroll
  for (int m = 1; m < 64; m <<= 1) ss += __shfl_xor(ss, m, 64);
  float sc = rsqrtf(ss * (1.0f / DM) + EPSV);
  const float* gp = g + lane * 8;
  if (F32OUT) {
    float* o = (float*)outp + (size_t)row * DM + lane * 8;
    f32x4 o0, o1;
#pragma unroll
    for (int j = 0; j < 4; j++) { o0[j] = a[j] * sc * gp[j]; o1[j] = b[j] * sc * gp[4 + j]; }
    *(f32x4*)o = o0;
    *(f32x4*)(o + 4) = o1;
  } else {
    s16x8 o;
#pragma unroll
    for (int j = 0; j < 4; j++) { o[j] = f2b(a[j] * sc * gp[j]); o[4 + j] = f2b(b[j] * sc * gp[4 + j]); }
    *(s16x8*)((short*)outp + (size_t)row * DM + lane * 8) = o;
  }
}

// ---------------- SwiGLU elementwise: a = silu(a) * b (in place) ----------------
__global__ void swiglu_kernel(short* __restrict__ a, const short* __restrict__ g3, int n8) {
  int i = blockIdx.x * 256 + threadIdx.x;
  if (i >= n8) return;
  s16x8 va = ((const s16x8*)a)[i];
  s16x8 vb = ((const s16x8*)g3)[i];
  s16x8 o;
#pragma unroll
  for (int j = 0; j < 8; j++) {
    float xv = b2f(va[j]);
    float yv = b2f(vb[j]);
    float s = xv / (1.0f + __expf(-xv));
    o[j] = f2b(s * yv);
  }
  ((s16x8*)a)[i] = o;
}

// ---------------- GEMM: out[M,N] = A[M,K] @ W[N,K]^T (both bf16, K contiguous) ----------------
// 4 waves in 2x2; per-wave ARx AC 16x16 fragments. BM=AR*32, BN=AC*32, BK=32.
// LDS XOR-swizzled (granule ^= (row>>1)&3) with pre-swizzled global source for
// global_load_lds (rule #21: both sides or neither).
// FUSE==0: write bf16 to outb. FUSE==1: outf[idx] += acc (fp32 residual, in place).
template<int AR, int AC, int FUSE>
__global__ __launch_bounds__(256) void gemm_bt(const short* __restrict__ A, const short* __restrict__ W,
                                               short* __restrict__ outb, float* __restrict__ outf,
                                               int N, int K) {
  constexpr int BM = AR * 32;
  constexpr int BN = AC * 32;
  __shared__ short As[BM * 32];
  __shared__ short Bs[BN * 32];
  const int tid = threadIdx.x;
  const int lane = tid & 63;
  const int w = tid >> 6;
  const int wr = w >> 1, wc = w & 1;
  const int m0 = blockIdx.x * BM, n0 = blockIdx.y * BN;
  f32x4 acc[AR][AC] = {};
  for (int k = 0; k < K; k += 32) {
    __syncthreads();  // prior iter's readers done before overwrite
#pragma unroll
    for (int i = 0; i < BM / 64; i++) {
      int s = i * 256 + tid;
      int row = s >> 2, gl = s & 3, gd = gl ^ ((row >> 1) & 3);
      GLLDS(A + (size_t)(m0 + row) * K + k + gd * 8, (char*)As + (i * 256 + w * 64) * 16);
    }
#pragma unroll
    for (int i = 0; i < BN / 64; i++) {
      int s = i * 256 + tid;
      int row = s >> 2, gl = s & 3, gd = gl ^ ((row >> 1) & 3);
      GLLDS(W + (size_t)(n0 + row) * K + k + gd * 8, (char*)Bs + (i * 256 + w * 64) * 16);
    }
    __syncthreads();  // vmcnt(0) drained by compiler before barrier
    s16x8 af[AR], bf[AC];
#pragma unroll
    for (int i = 0; i < AR; i++) {
      int row = wr * AR * 16 + i * 16 + (lane & 15);
      int gl = (lane >> 4) ^ ((row >> 1) & 3);
      af[i] = *(const s16x8*)(As + row * 32 + gl * 8);
    }
#pragma unroll
    for (int j = 0; j < AC; j++) {
      int row = wc * AC * 16 + j * 16 + (lane & 15);
      int gl = (lane >> 4) ^ ((row >> 1) & 3);
      bf[j] = *(const s16x8*)(Bs + row * 32 + gl * 8);
    }
#pragma unroll
    for (int i = 0; i < AR; i++)
#pragma unroll
      for (int j = 0; j < AC; j++)
        acc[i][j] = MFMA_BF16(af[i], bf[j], acc[i][j]);
  }
  // C/D layout: col = lane&15, row = (lane>>4)*4 + reg  [m89-verified]
#pragma unroll
  for (int i = 0; i < AR; i++) {
    int rbase = m0 + wr * AR * 16 + i * 16 + (lane >> 4) * 4;
#pragma unroll
    for (int j = 0; j < AC; j++) {
      int col = n0 + wc * AC * 16 + j * 16 + (lane & 15);
#pragma unroll
      for (int r = 0; r < 4; r++) {
        size_t idx = (size_t)(rbase + r) * N + col;
        if (FUSE == 0) outb[idx] = f2b(acc[i][j][r]);
        else           outf[idx] += acc[i][j][r];
      }
    }
  }
}

// ---------------- Flash attention: one (b,h) x 64 q-rows per block ----------------
// 4 waves, each owns 16 q rows. K tile [64,64] in LDS (XOR-swizzled granules),
// V tile transposed [d][k] in LDS (swizzled), P round-trips through LDS as bf16.
__global__ __launch_bounds__(256) void attn_kernel(const short* __restrict__ Qb, const short* __restrict__ Kb,
                                                   const short* __restrict__ Vb, const int* __restrict__ ids,
                                                   short* __restrict__ Ob) {
  const int bh = blockIdx.x;
  const int bb = bh >> 3, hh = bh & 7;
  const int q0 = blockIdx.y * 64;
  const int tid = threadIdx.x, lane = tid & 63, w = tid >> 6;
  __shared__ short Kl[64 * 64];
  __shared__ short Vt[64 * 64];
  __shared__ short Pl[4][16 * 64];
  const size_t hbase = (size_t)bb * SEQ * DM + hh * 64;
  s16x8 qf0, qf1;
  {
    int qrow = q0 + w * 16 + (lane & 15);
    const short* qp = Qb + hbase + (size_t)qrow * DM + (lane >> 4) * 8;
    qf0 = *(const s16x8*)qp;
    qf1 = *(const s16x8*)(qp + 32);
  }
  int qid[4];
  if (ids) {
    int qr = q0 + w * 16 + (lane >> 4) * 4;
#pragma unroll
    for (int r = 0; r < 4; r++) qid[r] = ids[bb * SEQ + qr + r];
  }
  float m_[4], l_[4];
  f32x4 oacc[4] = {};
#pragma unroll
  for (int r = 0; r < 4; r++) { m_[r] = -1e30f; l_[r] = 0.f; }

  for (int kt = 0; kt < SEQ; kt += 64) {
    __syncthreads();
    // stage K rows [kt,kt+64), head slice; swizzled via pre-swizzled global src
#pragma unroll
    for (int i = 0; i < 2; i++) {
      int s = i * 256 + tid;
      int row = s >> 3, gl = s & 7, gd = gl ^ (row & 7);
      GLLDS(Kb + hbase + (size_t)(kt + row) * DM + gd * 8, (char*)Kl + (i * 256 + w * 64) * 16);
    }
    // stage V transposed: Vt[d][k], swizzled granules
#pragma unroll
    for (int i = 0; i < 2; i++) {
      int s = i * 256 + tid;
      int vr = s >> 3, c0 = (s & 7) * 8;
      s16x8 vv = *(const s16x8*)(Vb + hbase + (size_t)(kt + vr) * DM + c0);
#pragma unroll
      for (int j = 0; j < 8; j++) {
        int d = c0 + j;
        Vt[d * 64 + (((vr >> 3) ^ (d & 7)) * 8) + (vr & 7)] = vv[j];
      }
    }
    __syncthreads();
    // QK^T: sc[kc][r] = S[q0+w*16+(lane>>4)*4+r][kt+kc*16+(lane&15)]
    f32x4 sc[4];
    int kid[4];
#pragma unroll
    for (int kc = 0; kc < 4; kc++) {
      int krow = kc * 16 + (lane & 15);
      s16x8 kf0 = *(const s16x8*)(Kl + krow * 64 + (((lane >> 4) ^ (krow & 7)) * 8));
      s16x8 kf1 = *(const s16x8*)(Kl + krow * 64 + (((4 + (lane >> 4)) ^ (krow & 7)) * 8));
      f32x4 s4 = {};
      s4 = MFMA_BF16(qf0, kf0, s4);
      s4 = MFMA_BF16(qf1, kf1, s4);
      sc[kc] = s4;
      if (ids) kid[kc] = ids[bb * SEQ + kt + kc * 16 + (lane & 15)];
    }
    // online softmax (fp32); 16-lane group shuffles reduce across score cols
    float pr[4][4];
#pragma unroll
    for (int r = 0; r < 4; r++) {
      float s0 = sc[0][r] * 0.125f, s1 = sc[1][r] * 0.125f;
      float s2 = sc[2][r] * 0.125f, s3 = sc[3][r] * 0.125f;
      if (ids) {
        if (kid[0] != qid[r]) s0 = -1e30f;
        if (kid[1] != qid[r]) s1 = -1e30f;
        if (kid[2] != qid[r]) s2 = -1e30f;
        if (kid[3] != qid[r]) s3 = -1e30f;
      }
      float mx = fmaxf(fmaxf(s0, s1), fmaxf(s2, s3));
#pragma unroll
      for (int dlt = 1; dlt < 16; dlt <<= 1) mx = fmaxf(mx, __shfl_xor(mx, dlt, 16));
      float nm = fmaxf(m_[r], mx);
      float c = __expf(m_[r] - nm);
      m_[r] = nm;
      l_[r] *= c;
      oacc[0][r] *= c; oacc[1][r] *= c; oacc[2][r] *= c; oacc[3][r] *= c;
      float p0 = __expf(s0 - nm), p1 = __expf(s1 - nm);
      float p2 = __expf(s2 - nm), p3 = __expf(s3 - nm);
      pr[0][r] = p0; pr[1][r] = p1; pr[2][r] = p2; pr[3][r] = p3;
      float sum = p0 + p1 + p2 + p3;
#pragma unroll
      for (int dlt = 1; dlt < 16; dlt <<= 1) sum += __shfl_xor(sum, dlt, 16);
      l_[r] += sum;
    }
    // write P (bf16) to per-wave LDS slice, swizzled
#pragma unroll
    for (int kc = 0; kc < 4; kc++) {
#pragma unroll
      for (int r = 0; r < 4; r++) {
        int prow = (lane >> 4) * 4 + r;
        int col = kc * 16 + (lane & 15);
        Pl[w][prow * 64 + (((col >> 3) ^ (prow & 7)) * 8) + (col & 7)] = f2b(pr[kc][r]);
      }
    }
    // PV: oacc[dt] += P[16x64] @ V[64x16(dt)]
#pragma unroll
    for (int ks = 0; ks < 2; ks++) {
      int prow = lane & 15;
      s16x8 pf = *(const s16x8*)(&Pl[w][prow * 64 + (((ks * 4 + (lane >> 4)) ^ (prow & 7)) * 8)]);
#pragma unroll
      for (int dt = 0; dt < 4; dt++) {
        int vrow = dt * 16 + (lane & 15);
        s16x8 vf = *(const s16x8*)(Vt + vrow * 64 + (((ks * 4 + (lane >> 4)) ^ (vrow & 7)) * 8));
        oacc[dt] = MFMA_BF16(pf, vf, oacc[dt]);
      }
    }
  }
#pragma unroll
  for (int dt = 0; dt < 4; dt++) {
#pragma unroll
    for (int r = 0; r < 4; r++) {
      int q = q0 + w * 16 + (lane >> 4) * 4 + r;
      Ob[hbase + (size_t)q * DM + dt * 16 + (lane & 15)] = f2b(oacc[dt][r] / l_[r]);
    }
  }
}

// ---------------- host ----------------
extern "C" void kernel_launch(void* const* d_in, const int* in_sizes, int n_in,
                              void* d_out, int out_size, void* d_ws, size_t ws_size,
                              hipStream_t stream) {
  const float* x_in  = (const float*)d_in[0];
  const int* col_ids = (const int*)d_in[1];
  const int* row_ids = (const int*)d_in[2];
  const int* nbr_ids = (const int*)d_in[3];
  const float* g_attn = (const float*)d_in[11];
  const float* g_ffn  = (const float*)d_in[12];
  const float* g_out  = (const float*)d_in[13];

  char* ws = (char*)d_ws;
  float* x  = (float*)(ws);
  short* h  = (short*)(ws + (size_t)(8u  << 20));
  short* qb = (short*)(ws + (size_t)(12u << 20));
  short* kb = (short*)(ws + (size_t)(16u << 20));
  short* vb = (short*)(ws + (size_t)(20u << 20));
  short* ob = (short*)(ws + (size_t)(24u << 20));
  short* fa = (short*)(ws + (size_t)(28u << 20));
  short* fb = (short*)(ws + (size_t)(44u << 20));
  short* wqb = (short*)(ws + (size_t)(60u  << 20));
  short* wkb = (short*)(ws + (size_t)(68u  << 20));
  short* wvb = (short*)(ws + (size_t)(76u  << 20));
  short* wob = (short*)(ws + (size_t)(84u  << 20));
  short* w1b = (short*)(ws + (size_t)(92u  << 20));
  short* w3b = (short*)(ws + (size_t)(100u << 20));
  short* w2b = (short*)(ws + (size_t)(108u << 20));

  // all 7 weight arrays have 4*4*512*512 == 4*2048*512 == 4194304 elements
  const int NWEL = 4194304;
  const void* srcs[7] = {d_in[4], d_in[5], d_in[6], d_in[7], d_in[8], d_in[9], d_in[10]};
  short* dsts[7] = {wqb, wkb, wvb, wob, w1b, w3b, w2b};
  for (int i = 0; i < 7; i++)
    cvt_kernel<<<NWEL / 1024, 256, 0, stream>>>((const f32x4*)srcs[i], (s16x4*)dsts[i], NWEL / 4);

  hipMemcpyAsync(x, x_in, (size_t)MTOT * DM * 4, hipMemcpyDeviceToDevice, stream);

  const int* idsarr[4] = {col_ids, row_ids, nbr_ids, nullptr};

  for (int l = 0; l < 4; l++) {
    for (int r = 0; r < 4; r++) {
      rmsnorm_kernel<false><<<1024, 256, 0, stream>>>(x, g_attn + (size_t)(l * 4 + r) * DM, (void*)h);
      size_t woff = (size_t)(l * 4 + r) * DM * DM;
      gemm_bt<4, 2, 0><<<dim3(32, 8), 256, 0, stream>>>(h, wqb + woff, qb, nullptr, DM, DM);
      gemm_bt<4, 2, 0><<<dim3(32, 8), 256, 0, stream>>>(h, wkb + woff, kb, nullptr, DM, DM);
      gemm_bt<4, 2, 0><<<dim3(32, 8), 256, 0, stream>>>(h, wvb + woff, vb, nullptr, DM, DM);
      attn_kernel<<<dim3(32, 16), 256, 0, stream>>>(qb, kb, vb, idsarr[r], ob);
      gemm_bt<4, 2, 1><<<dim3(32, 8), 256, 0, stream>>>(ob, wob + woff, nullptr, x, DM, DM);
    }
    rmsnorm_kernel<false><<<1024, 256, 0, stream>>>(x, g_ffn + (size_t)l * DM, (void*)h);
    size_t foff = (size_t)l * 2048 * DM;
    gemm_bt<4, 4, 0><<<dim3(32, 16), 256, 0, stream>>>(h, w1b + foff, fa, nullptr, 2048, DM);
    gemm_bt<4, 4, 0><<<dim3(32, 16), 256, 0, stream>>>(h, w3b + foff, fb, nullptr, 2048, DM);
    swiglu_kernel<<<4096, 256, 0, stream>>>(fa, fb, MTOT * 2048 / 8);
    gemm_bt<4, 2, 1><<<dim3(32, 8), 256, 0, stream>>>(fa, w2b + foff, nullptr, x, DM, 2048);
  }
  rmsnorm_kernel<true><<<1024, 256, 0, stream>>>(x, g_out, d_out);
}

// Round 2
// 1515.801 us; speedup vs baseline: 1.3732x; 1.3732x over previous
//
#include <hip/hip_runtime.h>
#include <hip/hip_bf16.h>

// RelationalTransformer forward on MI355X (gfx950). Round 1.
// bf16 MFMA everywhere; fp32 residual. V pre-transposed per layer so the
// flash-attn kernel stages K and V^T with global_load_lds (no scatter).
// Workspace (<=116MB, matches R0 footprint):
//   [0,8M)    x     fp32 [4096,512]
//   [8M,12M)  h     bf16 [4096,512]
//   [12M,24M) qkv   bf16 [4096,1536]        (attn phase)
//   [24M,28M) vt    bf16 [32bh,64,1024]     (attn phase)
//   [28M,32M) ob    bf16 [4096,512]         (attn phase)
//   [12M,44M) f     bf16 [4096,4096]        (ffn phase, overlaps attn bufs)
//   [44M,60M) fa    bf16 [4096,2048]
//   [60M,116M) weights: wqkv 24M | wo 8M | w13 16M | w2 8M

typedef __attribute__((ext_vector_type(4))) float f32x4;
typedef __attribute__((ext_vector_type(8))) short s16x8;
typedef __attribute__((ext_vector_type(4))) short s16x4;

#define SEQ 1024
#define DM 512
#define MTOT 4096
#define EPSV 1.1920929e-07f

static __device__ __forceinline__ float b2f(short s) {
  unsigned u = ((unsigned)(unsigned short)s) << 16;
  return __builtin_bit_cast(float, u);
}
static __device__ __forceinline__ short f2b(float f) {
  unsigned u = __builtin_bit_cast(unsigned, f);
  u = (u + 0x7fffu + ((u >> 16) & 1u)) >> 16;  // RNE; inputs never NaN
  return (short)(unsigned short)u;
}

#define MFMA_BF16(a, b, c) __builtin_amdgcn_mfma_f32_16x16x32_bf16((a), (b), (c), 0, 0, 0)
#define GLLDS(gp, lp)                                                                        \
  __builtin_amdgcn_global_load_lds((const __attribute__((address_space(1))) unsigned*)(gp),  \
                                   (__attribute__((address_space(3))) unsigned*)(lp), 16, 0, 0)

// ---------------- fp32 -> bf16 weight conversion with placement ----------------
// dst[(i>>shift)*stride4 + off4 + (i & ((1<<shift)-1))] = bf16(src[i]); units of 4 elems.
__global__ void cvt_place(const f32x4* __restrict__ src, s16x4* __restrict__ dst, int n4,
                          int shift, int stride4, int off4) {
  int i = blockIdx.x * 256 + threadIdx.x;
  if (i >= n4) return;
  f32x4 v = src[i];
  s16x4 o;
  o[0] = f2b(v[0]); o[1] = f2b(v[1]); o[2] = f2b(v[2]); o[3] = f2b(v[3]);
  int c = i >> shift, r = i & ((1 << shift) - 1);
  dst[(size_t)c * stride4 + off4 + r] = o;
}

// ---------------- RMSNorm: one wave per row ----------------
template<bool F32OUT>
__global__ void rmsnorm_kernel(const float* __restrict__ x, const float* __restrict__ g,
                               void* __restrict__ outp) {
  int row = blockIdx.x * 4 + (threadIdx.x >> 6);
  int lane = threadIdx.x & 63;
  const float* xr = x + (size_t)row * DM + lane * 8;
  f32x4 a = *(const f32x4*)xr;
  f32x4 b = *(const f32x4*)(xr + 4);
  float ss = a[0]*a[0]+a[1]*a[1]+a[2]*a[2]+a[3]*a[3]+b[0]*b[0]+b[1]*b[1]+b[2]*b[2]+b[3]*b[3];
#pragma unroll
  for (int m = 1; m < 64; m <<= 1) ss += __shfl_xor(ss, m, 64);
  float sc = rsqrtf(ss * (1.0f / DM) + EPSV);
  const float* gp = g + lane * 8;
  if (F32OUT) {
    float* o = (float*)outp + (size_t)row * DM + lane * 8;
    f32x4 o0, o1;
#pragma unroll
    for (int j = 0; j < 4; j++) { o0[j] = a[j] * sc * gp[j]; o1[j] = b[j] * sc * gp[4 + j]; }
    *(f32x4*)o = o0;
    *(f32x4*)(o + 4) = o1;
  } else {
    s16x8 o;
#pragma unroll
    for (int j = 0; j < 4; j++) { o[j] = f2b(a[j] * sc * gp[j]); o[4 + j] = f2b(b[j] * sc * gp[4 + j]); }
    *(s16x8*)((short*)outp + (size_t)row * DM + lane * 8) = o;
  }
}

// ---------------- SwiGLU: fa[m][j] = silu(f[m][j]) * f[m][2048+j] ----------------
__global__ void swiglu_kernel(const short* __restrict__ f, short* __restrict__ fa, int n8) {
  int i = blockIdx.x * 256 + threadIdx.x;
  if (i >= n8) return;
  int row = i >> 8, c8 = i & 255;
  s16x8 va = *(const s16x8*)(f + (size_t)row * 4096 + c8 * 8);
  s16x8 vb = *(const s16x8*)(f + (size_t)row * 4096 + 2048 + c8 * 8);
  s16x8 o;
#pragma unroll
  for (int j = 0; j < 8; j++) {
    float xv = b2f(va[j]);
    float yv = b2f(vb[j]);
    float s = xv / (1.0f + __expf(-xv));
    o[j] = f2b(s * yv);
  }
  *(s16x8*)(fa + (size_t)row * 2048 + c8 * 8) = o;
}

// ---------------- V transpose: qkv[:,1024+h*64+d] -> vt[bh][d][s] ----------------
__global__ __launch_bounds__(256) void vtrans_kernel(const short* __restrict__ qkv, short* __restrict__ vt) {
  int bh = blockIdx.x, st = blockIdx.y;
  int bb = bh >> 3, hh = bh & 7;
  __shared__ short t[64][72];  // [d][s], padded rows (144B, 16B-aligned)
  int tid = threadIdx.x;
  const short* src = qkv + (size_t)(bb * SEQ + st * 64) * 1536 + 1024 + hh * 64;
#pragma unroll
  for (int i = 0; i < 2; i++) {
    int s = i * 256 + tid;
    int r = s >> 3, c = (s & 7) * 8;  // r: s-row, c: d base
    s16x8 v = *(const s16x8*)(src + (size_t)r * 1536 + c);
#pragma unroll
    for (int j = 0; j < 8; j++) t[c + j][r] = v[j];
  }
  __syncthreads();
  short* dst = vt + (size_t)bh * 64 * SEQ + st * 64;
#pragma unroll
  for (int i = 0; i < 2; i++) {
    int s = i * 256 + tid;
    int d = s >> 3, c = (s & 7) * 8;  // d: out row, c: s base
    s16x8 o = *(const s16x8*)(&t[d][c]);
    *(s16x8*)(dst + (size_t)d * SEQ + c) = o;
  }
}

// ---------------- GEMM: out[M,N] = A[M,K] @ W[N,K]^T ----------------
template<int AR, int AC, int FUSE>
__global__ __launch_bounds__(256) void gemm_bt(const short* __restrict__ A, const short* __restrict__ W,
                                               short* __restrict__ outb, float* __restrict__ outf,
                                               int N, int K) {
  constexpr int BM = AR * 32;
  constexpr int BN = AC * 32;
  __shared__ short As[BM * 32];
  __shared__ short Bs[BN * 32];
  const int tid = threadIdx.x;
  const int lane = tid & 63;
  const int w = tid >> 6;
  const int wr = w >> 1, wc = w & 1;
  const int m0 = blockIdx.x * BM, n0 = blockIdx.y * BN;
  f32x4 acc[AR][AC] = {};
  for (int k = 0; k < K; k += 32) {
    __syncthreads();
#pragma unroll
    for (int i = 0; i < BM / 64; i++) {
      int s = i * 256 + tid;
      int row = s >> 2, gl = s & 3, gd = gl ^ ((row >> 1) & 3);
      GLLDS(A + (size_t)(m0 + row) * K + k + gd * 8, (char*)As + (i * 256 + w * 64) * 16);
    }
#pragma unroll
    for (int i = 0; i < BN / 64; i++) {
      int s = i * 256 + tid;
      int row = s >> 2, gl = s & 3, gd = gl ^ ((row >> 1) & 3);
      GLLDS(W + (size_t)(n0 + row) * K + k + gd * 8, (char*)Bs + (i * 256 + w * 64) * 16);
    }
    __syncthreads();
    s16x8 af[AR], bf[AC];
#pragma unroll
    for (int i = 0; i < AR; i++) {
      int row = wr * AR * 16 + i * 16 + (lane & 15);
      int gl = (lane >> 4) ^ ((row >> 1) & 3);
      af[i] = *(const s16x8*)(As + row * 32 + gl * 8);
    }
#pragma unroll
    for (int j = 0; j < AC; j++) {
      int row = wc * AC * 16 + j * 16 + (lane & 15);
      int gl = (lane >> 4) ^ ((row >> 1) & 3);
      bf[j] = *(const s16x8*)(Bs + row * 32 + gl * 8);
    }
#pragma unroll
    for (int i = 0; i < AR; i++)
#pragma unroll
      for (int j = 0; j < AC; j++)
        acc[i][j] = MFMA_BF16(af[i], bf[j], acc[i][j]);
  }
#pragma unroll
  for (int i = 0; i < AR; i++) {
    int rbase = m0 + wr * AR * 16 + i * 16 + (lane >> 4) * 4;
#pragma unroll
    for (int j = 0; j < AC; j++) {
      int col = n0 + wc * AC * 16 + j * 16 + (lane & 15);
#pragma unroll
      for (int r = 0; r < 4; r++) {
        size_t idx = (size_t)(rbase + r) * N + col;
        if (FUSE == 0) outb[idx] = f2b(acc[i][j][r]);
        else           outf[idx] += acc[i][j][r];
      }
    }
  }
}

// ---------------- Flash attention ----------------
// Q,K from qkv[4096][1536] (q at col h*64, k at col 512+h*64); V^T from vt[bh][64][1024].
// 4 waves x 16 q rows; K tile and V^T tile staged via global_load_lds (swizzled).
__global__ __launch_bounds__(256) void attn_kernel(const short* __restrict__ qkv, const short* __restrict__ vt,
                                                   const int* __restrict__ ids, short* __restrict__ Ob) {
  const int bh = blockIdx.x;
  const int bb = bh >> 3, hh = bh & 7;
  const int q0 = blockIdx.y * 64;
  const int tid = threadIdx.x, lane = tid & 63, w = tid >> 6;
  __shared__ short Kl[64 * 64];
  __shared__ short Vl[64 * 64];   // [d][k] tile of V^T
  __shared__ short Pl[4][16 * 64];
  const short* kbase = qkv + 512 + hh * 64;
  const short* vbase = vt + (size_t)bh * 64 * SEQ;
  s16x8 qf0, qf1;
  {
    int qrow = q0 + w * 16 + (lane & 15);
    const short* qp = qkv + (size_t)(bb * SEQ + qrow) * 1536 + hh * 64 + (lane >> 4) * 8;
    qf0 = *(const s16x8*)qp;
    qf1 = *(const s16x8*)(qp + 32);
  }
  int qid[4];
  if (ids) {
    int qr = q0 + w * 16 + (lane >> 4) * 4;
#pragma unroll
    for (int r = 0; r < 4; r++) qid[r] = ids[bb * SEQ + qr + r];
  }
  float m_[4], l_[4];
  f32x4 oacc[4] = {};
#pragma unroll
  for (int r = 0; r < 4; r++) { m_[r] = -1e30f; l_[r] = 0.f; }

  for (int kt = 0; kt < SEQ; kt += 64) {
    __syncthreads();
#pragma unroll
    for (int i = 0; i < 2; i++) {
      int s = i * 256 + tid;
      int row = s >> 3, gl = s & 7, gd = gl ^ (row & 7);
      GLLDS(kbase + (size_t)(bb * SEQ + kt + row) * 1536 + gd * 8, (char*)Kl + (i * 256 + w * 64) * 16);
    }
#pragma unroll
    for (int i = 0; i < 2; i++) {
      int s = i * 256 + tid;
      int row = s >> 3, gl = s & 7, gd = gl ^ (row & 7);   // row = d index
      GLLDS(vbase + (size_t)row * SEQ + kt + gd * 8, (char*)Vl + (i * 256 + w * 64) * 16);
    }
    __syncthreads();
    // QK^T
    f32x4 sc[4];
    int kid[4];
#pragma unroll
    for (int kc = 0; kc < 4; kc++) {
      int krow = kc * 16 + (lane & 15);
      s16x8 kf0 = *(const s16x8*)(Kl + krow * 64 + (((lane >> 4) ^ (krow & 7)) * 8));
      s16x8 kf1 = *(const s16x8*)(Kl + krow * 64 + (((4 + (lane >> 4)) ^ (krow & 7)) * 8));
      f32x4 s4 = {};
      s4 = MFMA_BF16(qf0, kf0, s4);
      s4 = MFMA_BF16(qf1, kf1, s4);
      sc[kc] = s4;
      if (ids) kid[kc] = ids[bb * SEQ + kt + kc * 16 + (lane & 15)];
    }
    // online softmax
    float pr[4][4];
#pragma unroll
    for (int r = 0; r < 4; r++) {
      float s0 = sc[0][r] * 0.125f, s1 = sc[1][r] * 0.125f;
      float s2 = sc[2][r] * 0.125f, s3 = sc[3][r] * 0.125f;
      if (ids) {
        if (kid[0] != qid[r]) s0 = -1e30f;
        if (kid[1] != qid[r]) s1 = -1e30f;
        if (kid[2] != qid[r]) s2 = -1e30f;
        if (kid[3] != qid[r]) s3 = -1e30f;
      }
      float mx = fmaxf(fmaxf(s0, s1), fmaxf(s2, s3));
#pragma unroll
      for (int dlt = 1; dlt < 16; dlt <<= 1) mx = fmaxf(mx, __shfl_xor(mx, dlt, 16));
      float nm = fmaxf(m_[r], mx);
      float c = __expf(m_[r] - nm);
      m_[r] = nm;
      l_[r] *= c;
      oacc[0][r] *= c; oacc[1][r] *= c; oacc[2][r] *= c; oacc[3][r] *= c;
      float p0 = __expf(s0 - nm), p1 = __expf(s1 - nm);
      float p2 = __expf(s2 - nm), p3 = __expf(s3 - nm);
      pr[0][r] = p0; pr[1][r] = p1; pr[2][r] = p2; pr[3][r] = p3;
      float sum = p0 + p1 + p2 + p3;
#pragma unroll
      for (int dlt = 1; dlt < 16; dlt <<= 1) sum += __shfl_xor(sum, dlt, 16);
      l_[r] += sum;
    }
    // P -> per-wave LDS (bf16, swizzled)
#pragma unroll
    for (int kc = 0; kc < 4; kc++) {
#pragma unroll
      for (int r = 0; r < 4; r++) {
        int prow = (lane >> 4) * 4 + r;
        int col = kc * 16 + (lane & 15);
        Pl[w][prow * 64 + (((col >> 3) ^ (prow & 7)) * 8) + (col & 7)] = f2b(pr[kc][r]);
      }
    }
    // PV
#pragma unroll
    for (int ks = 0; ks < 2; ks++) {
      int prow = lane & 15;
      s16x8 pf = *(const s16x8*)(&Pl[w][prow * 64 + (((ks * 4 + (lane >> 4)) ^ (prow & 7)) * 8)]);
#pragma unroll
      for (int dt = 0; dt < 4; dt++) {
        int vrow = dt * 16 + (lane & 15);
        s16x8 vf = *(const s16x8*)(Vl + vrow * 64 + (((ks * 4 + (lane >> 4)) ^ (vrow & 7)) * 8));
        oacc[dt] = MFMA_BF16(pf, vf, oacc[dt]);
      }
    }
  }
  const size_t obase = (size_t)(bb * SEQ) * DM + hh * 64;
#pragma unroll
  for (int dt = 0; dt < 4; dt++) {
#pragma unroll
    for (int r = 0; r < 4; r++) {
      int q = q0 + w * 16 + (lane >> 4) * 4 + r;
      Ob[obase + (size_t)q * DM + dt * 16 + (lane & 15)] = f2b(oacc[dt][r] / l_[r]);
    }
  }
}

// ---------------- host ----------------
extern "C" void kernel_launch(void* const* d_in, const int* in_sizes, int n_in,
                              void* d_out, int out_size, void* d_ws, size_t ws_size,
                              hipStream_t stream) {
  const float* x_in  = (const float*)d_in[0];
  const int* col_ids = (const int*)d_in[1];
  const int* row_ids = (const int*)d_in[2];
  const int* nbr_ids = (const int*)d_in[3];
  const float* g_attn = (const float*)d_in[11];
  const float* g_ffn  = (const float*)d_in[12];
  const float* g_out  = (const float*)d_in[13];

  char* ws = (char*)d_ws;
  float* x   = (float*)(ws);
  short* h   = (short*)(ws + (size_t)(8u  << 20));
  short* qkv = (short*)(ws + (size_t)(12u << 20));
  short* vt  = (short*)(ws + (size_t)(24u << 20));
  short* ob  = (short*)(ws + (size_t)(28u << 20));
  short* f   = (short*)(ws + (size_t)(12u << 20));  // ffn phase, overlaps qkv/vt/ob
  short* fa  = (short*)(ws + (size_t)(44u << 20));
  short* wqkv = (short*)(ws + (size_t)(60u  << 20));  // [16][1536][512]
  short* wob  = (short*)(ws + (size_t)(84u  << 20));  // [16][512][512]
  short* w13  = (short*)(ws + (size_t)(92u  << 20));  // [4][4096][512]
  short* w2b  = (short*)(ws + (size_t)(108u << 20));  // [4][512][2048]

  const int N4 = 1048576;  // 4M elems / 4 per weight array
  // pack Wq/Wk/Wv into wqkv slots, W1/W3 into w13 slots
  cvt_place<<<4096, 256, 0, stream>>>((const f32x4*)d_in[4], (s16x4*)wqkv, N4, 16, 196608, 0);
  cvt_place<<<4096, 256, 0, stream>>>((const f32x4*)d_in[5], (s16x4*)wqkv, N4, 16, 196608, 65536);
  cvt_place<<<4096, 256, 0, stream>>>((const f32x4*)d_in[6], (s16x4*)wqkv, N4, 16, 196608, 131072);
  cvt_place<<<4096, 256, 0, stream>>>((const f32x4*)d_in[7], (s16x4*)wob,  N4, 20, 0, 0);
  cvt_place<<<4096, 256, 0, stream>>>((const f32x4*)d_in[8], (s16x4*)w13,  N4, 18, 524288, 0);
  cvt_place<<<4096, 256, 0, stream>>>((const f32x4*)d_in[9], (s16x4*)w13,  N4, 18, 524288, 262144);
  cvt_place<<<4096, 256, 0, stream>>>((const f32x4*)d_in[10], (s16x4*)w2b, N4, 20, 0, 0);

  hipMemcpyAsync(x, x_in, (size_t)MTOT * DM * 4, hipMemcpyDeviceToDevice, stream);

  const int* idsarr[4] = {col_ids, row_ids, nbr_ids, nullptr};

  for (int l = 0; l < 4; l++) {
    for (int r = 0; r < 4; r++) {
      rmsnorm_kernel<false><<<1024, 256, 0, stream>>>(x, g_attn + (size_t)(l * 4 + r) * DM, (void*)h);
      size_t woff = (size_t)(l * 4 + r) * 1536 * DM;
      gemm_bt<4, 2, 0><<<dim3(32, 24), 256, 0, stream>>>(h, wqkv + woff, qkv, nullptr, 1536, DM);
      vtrans_kernel<<<dim3(32, 16), 256, 0, stream>>>(qkv, vt);
      attn_kernel<<<dim3(32, 16), 256, 0, stream>>>(qkv, vt, idsarr[r], ob);
      gemm_bt<2, 2, 1><<<dim3(64, 8), 256, 0, stream>>>(ob, wob + (size_t)(l * 4 + r) * DM * DM,
                                                        nullptr, x, DM, DM);
    }
    rmsnorm_kernel<false><<<1024, 256, 0, stream>>>(x, g_ffn + (size_t)l * DM, (void*)h);
    gemm_bt<4, 4, 0><<<dim3(32, 32), 256, 0, stream>>>(h, w13 + (size_t)l * 4096 * DM, f, nullptr, 4096, DM);
    swiglu_kernel<<<4096, 256, 0, stream>>>(f, fa, MTOT * 2048 / 8);
    gemm_bt<2, 2, 1><<<dim3(64, 8), 256, 0, stream>>>(fa, w2b + (size_t)l * DM * 2048, nullptr, x, DM, 2048);
  }
  rmsnorm_kernel<true><<<1024, 256, 0, stream>>>(x, g_out, d_out);
}

// Round 3
// 1253.371 us; speedup vs baseline: 1.6608x; 1.2094x over previous
//
#include <hip/hip_runtime.h>
#include <hip/hip_bf16.h>

// RelationalTransformer forward on MI355X (gfx950). Round 2.
// bf16 MFMA everywhere; fp32 residual. Swapped-QK^T flash attention with
// in-register softmax (each lane owns one q-row); V transposed directly in
// the QKV-GEMM epilogue (no vtrans kernel). Scale 1/8 folded into Wq.
// Workspace:
//   [0,8M)    x     fp32 [4096,512]
//   [8M,12M)  h     bf16 [4096,512]
//   [12M,24M) qkv   bf16 [4096,1536]   (q,k halves used; v written to vt)
//   [24M,28M) vt    bf16 [32bh][64d][1024s]
//   [28M,32M) ob    bf16 [4096,512]
//   [12M,44M) f     bf16 [4096,4096]   (ffn phase, overlaps attn bufs)
//   [44M,60M) fa    bf16 [4096,2048]
//   [60M,116M) weights: wqkv 24M | wo 8M | w13 16M | w2 8M

typedef __attribute__((ext_vector_type(4))) float f32x4;
typedef __attribute__((ext_vector_type(8))) short s16x8;
typedef __attribute__((ext_vector_type(4))) short s16x4;

#define SEQ 1024
#define DM 512
#define MTOT 4096
#define EPSV 1.1920929e-07f

static __device__ __forceinline__ float b2f(short s) {
  unsigned u = ((unsigned)(unsigned short)s) << 16;
  return __builtin_bit_cast(float, u);
}
static __device__ __forceinline__ short f2b(float f) {
  unsigned u = __builtin_bit_cast(unsigned, f);
  u = (u + 0x7fffu + ((u >> 16) & 1u)) >> 16;  // RNE; inputs never NaN
  return (short)(unsigned short)u;
}

#define MFMA_BF16(a, b, c) __builtin_amdgcn_mfma_f32_16x16x32_bf16((a), (b), (c), 0, 0, 0)
#define GLLDS(gp, lp)                                                                        \
  __builtin_amdgcn_global_load_lds((const __attribute__((address_space(1))) unsigned*)(gp),  \
                                   (__attribute__((address_space(3))) unsigned*)(lp), 16, 0, 0)
#define GLLDS4(gp, lp)                                                                       \
  __builtin_amdgcn_global_load_lds((const __attribute__((address_space(1))) unsigned*)(gp),  \
                                   (__attribute__((address_space(3))) unsigned*)(lp), 4, 0, 0)

// ---------------- fp32 -> bf16 weight conversion with placement + scale ----------------
__global__ void cvt_place(const f32x4* __restrict__ src, s16x4* __restrict__ dst, int n4,
                          int shift, int stride4, int off4, float scale) {
  int i = blockIdx.x * 256 + threadIdx.x;
  if (i >= n4) return;
  f32x4 v = src[i];
  s16x4 o;
  o[0] = f2b(v[0] * scale); o[1] = f2b(v[1] * scale);
  o[2] = f2b(v[2] * scale); o[3] = f2b(v[3] * scale);
  int c = i >> shift, r = i & ((1 << shift) - 1);
  dst[(size_t)c * stride4 + off4 + r] = o;
}

// ---------------- RMSNorm: one wave per row ----------------
template<bool F32OUT>
__global__ void rmsnorm_kernel(const float* __restrict__ x, const float* __restrict__ g,
                               void* __restrict__ outp) {
  int row = blockIdx.x * 4 + (threadIdx.x >> 6);
  int lane = threadIdx.x & 63;
  const float* xr = x + (size_t)row * DM + lane * 8;
  f32x4 a = *(const f32x4*)xr;
  f32x4 b = *(const f32x4*)(xr + 4);
  float ss = a[0]*a[0]+a[1]*a[1]+a[2]*a[2]+a[3]*a[3]+b[0]*b[0]+b[1]*b[1]+b[2]*b[2]+b[3]*b[3];
#pragma unroll
  for (int m = 1; m < 64; m <<= 1) ss += __shfl_xor(ss, m, 64);
  float sc = rsqrtf(ss * (1.0f / DM) + EPSV);
  const float* gp = g + lane * 8;
  if (F32OUT) {
    float* o = (float*)outp + (size_t)row * DM + lane * 8;
    f32x4 o0, o1;
#pragma unroll
    for (int j = 0; j < 4; j++) { o0[j] = a[j] * sc * gp[j]; o1[j] = b[j] * sc * gp[4 + j]; }
    *(f32x4*)o = o0;
    *(f32x4*)(o + 4) = o1;
  } else {
    s16x8 o;
#pragma unroll
    for (int j = 0; j < 4; j++) { o[j] = f2b(a[j] * sc * gp[j]); o[4 + j] = f2b(b[j] * sc * gp[4 + j]); }
    *(s16x8*)((short*)outp + (size_t)row * DM + lane * 8) = o;
  }
}

// ---------------- SwiGLU: fa[m][j] = silu(f[m][j]) * f[m][2048+j] ----------------
__global__ void swiglu_kernel(const short* __restrict__ f, short* __restrict__ fa, int n8) {
  int i = blockIdx.x * 256 + threadIdx.x;
  if (i >= n8) return;
  int row = i >> 8, c8 = i & 255;
  s16x8 va = *(const s16x8*)(f + (size_t)row * 4096 + c8 * 8);
  s16x8 vb = *(const s16x8*)(f + (size_t)row * 4096 + 2048 + c8 * 8);
  s16x8 o;
#pragma unroll
  for (int j = 0; j < 8; j++) {
    float xv = b2f(va[j]);
    float yv = b2f(vb[j]);
    float s = xv / (1.0f + __expf(-xv));
    o[j] = f2b(s * yv);
  }
  *(s16x8*)(fa + (size_t)row * 2048 + c8 * 8) = o;
}

// ---------------- GEMM: out[M,N] = A[M,K] @ W[N,K]^T ----------------
// FUSE 0: bf16 out. FUSE 1: fp32 accumulate into outf. FUSE 2: qkv mode --
// cols <1024 -> bf16 out (q,k), cols >=1024 -> transposed V write to vtb.
template<int AR, int AC, int FUSE>
__global__ __launch_bounds__(256) void gemm_bt(const short* __restrict__ A, const short* __restrict__ W,
                                               short* __restrict__ outb, float* __restrict__ outf,
                                               short* __restrict__ vtb, int N, int K) {
  constexpr int BM = AR * 32;
  constexpr int BN = AC * 32;
  __shared__ short As[BM * 32];
  __shared__ short Bs[BN * 32];
  const int tid = threadIdx.x;
  const int lane = tid & 63;
  const int w = tid >> 6;
  const int wr = w >> 1, wc = w & 1;
  const int m0 = blockIdx.x * BM, n0 = blockIdx.y * BN;
  f32x4 acc[AR][AC] = {};
  for (int k = 0; k < K; k += 32) {
    __syncthreads();
#pragma unroll
    for (int i = 0; i < BM / 64; i++) {
      int s = i * 256 + tid;
      int row = s >> 2, gl = s & 3, gd = gl ^ ((row >> 1) & 3);
      GLLDS(A + (size_t)(m0 + row) * K + k + gd * 8, (char*)As + (i * 256 + w * 64) * 16);
    }
#pragma unroll
    for (int i = 0; i < BN / 64; i++) {
      int s = i * 256 + tid;
      int row = s >> 2, gl = s & 3, gd = gl ^ ((row >> 1) & 3);
      GLLDS(W + (size_t)(n0 + row) * K + k + gd * 8, (char*)Bs + (i * 256 + w * 64) * 16);
    }
    __syncthreads();
    s16x8 af[AR], bf[AC];
#pragma unroll
    for (int i = 0; i < AR; i++) {
      int row = wr * AR * 16 + i * 16 + (lane & 15);
      int gl = (lane >> 4) ^ ((row >> 1) & 3);
      af[i] = *(const s16x8*)(As + row * 32 + gl * 8);
    }
#pragma unroll
    for (int j = 0; j < AC; j++) {
      int row = wc * AC * 16 + j * 16 + (lane & 15);
      int gl = (lane >> 4) ^ ((row >> 1) & 3);
      bf[j] = *(const s16x8*)(Bs + row * 32 + gl * 8);
    }
#pragma unroll
    for (int i = 0; i < AR; i++)
#pragma unroll
      for (int j = 0; j < AC; j++)
        acc[i][j] = MFMA_BF16(af[i], bf[j], acc[i][j]);
  }
#pragma unroll
  for (int i = 0; i < AR; i++) {
    int rbase = m0 + wr * AR * 16 + i * 16 + (lane >> 4) * 4;
#pragma unroll
    for (int j = 0; j < AC; j++) {
      int col = n0 + wc * AC * 16 + j * 16 + (lane & 15);
      if (FUSE == 2 && col >= 1024) {
        // V transpose: vt[bh][d][s], 4 consecutive s per lane
        int bbv = rbase >> 10, s = rbase & 1023;
        int c = col - 1024, hhv = c >> 6, d = c & 63;
        s16x4 o4;
#pragma unroll
        for (int r = 0; r < 4; r++) o4[r] = f2b(acc[i][j][r]);
        *(s16x4*)(vtb + (((size_t)(bbv * 8 + hhv) * 64 + d) << 10) + s) = o4;
      } else {
#pragma unroll
        for (int r = 0; r < 4; r++) {
          size_t idx = (size_t)(rbase + r) * N + col;
          if (FUSE == 1) outf[idx] += acc[i][j][r];
          else           outb[idx] = f2b(acc[i][j][r]);
        }
      }
    }
  }
}

// ---------------- Flash attention, swapped QK^T, in-register softmax ----------------
// 4 waves x 16 q rows (64 q / block). Per lane: q = q0 + w*16 + (lane&15);
// per k-tile the lane holds 16 scores for its q (k = kc*16 + g*4 + r, g=lane>>4).
// PV k-slot map: mfma0 slots j=0..3 -> k=4g+j (kc0), j=4..7 -> k=16+4g+(j-4) (kc1);
// mfma1 same with +32. V B-fragment = two b64 reads per mfma from swizzled Vl.
__global__ __launch_bounds__(256) void attn_kernel(const short* __restrict__ qkv, const short* __restrict__ vt,
                                                   const int* __restrict__ ids, short* __restrict__ Ob) {
  const int bh = blockIdx.x;
  const int bb = bh >> 3, hh = bh & 7;
  const int q0 = blockIdx.y * 64;
  const int tid = threadIdx.x, lane = tid & 63, w = tid >> 6;
  const int g = lane >> 4, qi = lane & 15;
  __shared__ short Kl[64 * 64];
  __shared__ short Vl[64 * 64];   // [d][k], XOR-swizzled 16B granules
  __shared__ int Kid[64];
  const short* kbase = qkv + 512 + hh * 64;
  const short* vbase = vt + (size_t)bh * 64 * SEQ;
  s16x8 qf0, qf1;
  {
    int qrow = q0 + w * 16 + qi;
    const short* qp = qkv + (size_t)(bb * SEQ + qrow) * 1536 + hh * 64 + g * 8;
    qf0 = *(const s16x8*)qp;
    qf1 = *(const s16x8*)(qp + 32);
  }
  int qid = 0;
  if (ids) qid = ids[bb * SEQ + q0 + w * 16 + qi];
  float m_ = -1e30f, l_ = 0.f;
  f32x4 oacc[4] = {};  // [dt]; lane holds O[q'=g*4+r][d=dt*16+qi]

  for (int kt = 0; kt < SEQ; kt += 64) {
    __syncthreads();
#pragma unroll
    for (int i = 0; i < 2; i++) {
      int s = i * 256 + tid;
      int row = s >> 3, gl = s & 7, gd = gl ^ (row & 7);
      GLLDS(kbase + (size_t)(bb * SEQ + kt + row) * 1536 + gd * 8, (char*)Kl + (i * 256 + w * 64) * 16);
    }
#pragma unroll
    for (int i = 0; i < 2; i++) {
      int s = i * 256 + tid;
      int row = s >> 3, gl = s & 7, gd = gl ^ (row & 7);   // row = d index
      GLLDS(vbase + (size_t)row * SEQ + kt + gd * 8, (char*)Vl + (i * 256 + w * 64) * 16);
    }
    if (ids && w == 0) GLLDS4(ids + bb * SEQ + kt + lane, (char*)Kid);
    __syncthreads();
    // QK^T swapped: sc[kc][r] = S[k = kt+kc*16+g*4+r][q = q0+w*16+qi]
    f32x4 sc[4];
#pragma unroll
    for (int kc = 0; kc < 4; kc++) {
      int krow = kc * 16 + qi;
      s16x8 kf0 = *(const s16x8*)(Kl + krow * 64 + ((g ^ (krow & 7)) * 8));
      s16x8 kf1 = *(const s16x8*)(Kl + krow * 64 + (((4 + g) ^ (krow & 7)) * 8));
      f32x4 s4 = {};
      s4 = MFMA_BF16(kf0, qf0, s4);
      s4 = MFMA_BF16(kf1, qf1, s4);
      sc[kc] = s4;
    }
    float p[4][4];
#pragma unroll
    for (int kc = 0; kc < 4; kc++) {
#pragma unroll
      for (int r = 0; r < 4; r++) p[kc][r] = sc[kc][r];
    }
    if (ids) {
#pragma unroll
      for (int kc = 0; kc < 4; kc++) {
        int4 kid4 = *(const int4*)(Kid + kc * 16 + g * 4);
        if (kid4.x != qid) p[kc][0] = -1e30f;
        if (kid4.y != qid) p[kc][1] = -1e30f;
        if (kid4.z != qid) p[kc][2] = -1e30f;
        if (kid4.w != qid) p[kc][3] = -1e30f;
      }
    }
    // in-lane max over 16, then cross-lane over the 4 sibling lanes
    float mx = fmaxf(fmaxf(p[0][0], p[0][1]), fmaxf(p[0][2], p[0][3]));
#pragma unroll
    for (int kc = 1; kc < 4; kc++)
      mx = fmaxf(mx, fmaxf(fmaxf(p[kc][0], p[kc][1]), fmaxf(p[kc][2], p[kc][3])));
    mx = fmaxf(mx, __shfl_xor(mx, 16, 64));
    mx = fmaxf(mx, __shfl_xor(mx, 32, 64));
    float nm = fmaxf(m_, mx);
    float c = __expf(m_ - nm);
    m_ = nm;
    float sum = 0.f;
#pragma unroll
    for (int kc = 0; kc < 4; kc++) {
#pragma unroll
      for (int r = 0; r < 4; r++) {
        p[kc][r] = __expf(p[kc][r] - nm);
        sum += p[kc][r];
      }
    }
    sum += __shfl_xor(sum, 16, 64);
    sum += __shfl_xor(sum, 32, 64);
    l_ = l_ * c + sum;
    // rescale oacc: lane's oacc rows are q' = g*4+r; c for q' lives at lane pos q'
#pragma unroll
    for (int r = 0; r < 4; r++) {
      float cr = __shfl(c, g * 4 + r, 16);
      oacc[0][r] *= cr; oacc[1][r] *= cr; oacc[2][r] *= cr; oacc[3][r] *= cr;
    }
    // pack P to bf16 A-fragments
    s16x8 pa, pb;
#pragma unroll
    for (int r = 0; r < 4; r++) {
      pa[r] = f2b(p[0][r]); pa[4 + r] = f2b(p[1][r]);
      pb[r] = f2b(p[2][r]); pb[4 + r] = f2b(p[3][r]);
    }
    // PV: oacc[dt] += P @ V ; V fragment slots match P k-slot map
    int sw;
    const short* vrow;
#pragma unroll
    for (int dt = 0; dt < 4; dt++) {
      int dl = dt * 16 + qi;
      sw = dl & 7;
      vrow = Vl + dl * 64;
      s16x4 va0 = *(const s16x4*)(vrow + (((g >> 1) ^ sw) * 8) + (g & 1) * 4);
      s16x4 va1 = *(const s16x4*)(vrow + ((((g >> 1) + 2) ^ sw) * 8) + (g & 1) * 4);
      s16x4 vb0 = *(const s16x4*)(vrow + ((((g >> 1) + 4) ^ sw) * 8) + (g & 1) * 4);
      s16x4 vb1 = *(const s16x4*)(vrow + ((((g >> 1) + 6) ^ sw) * 8) + (g & 1) * 4);
      s16x8 vf0 = {va0[0], va0[1], va0[2], va0[3], va1[0], va1[1], va1[2], va1[3]};
      s16x8 vf1 = {vb0[0], vb0[1], vb0[2], vb0[3], vb1[0], vb1[1], vb1[2], vb1[3]};
      oacc[dt] = MFMA_BF16(pa, vf0, oacc[dt]);
      oacc[dt] = MFMA_BF16(pb, vf1, oacc[dt]);
    }
  }
  const size_t obase = (size_t)(bb * SEQ) * DM + hh * 64;
#pragma unroll
  for (int r = 0; r < 4; r++) {
    float lr = __shfl(l_, g * 4 + r, 16);
    float inv = 1.0f / lr;
    int q = q0 + w * 16 + g * 4 + r;
#pragma unroll
    for (int dt = 0; dt < 4; dt++)
      Ob[obase + (size_t)q * DM + dt * 16 + qi] = f2b(oacc[dt][r] * inv);
  }
}

// ---------------- host ----------------
extern "C" void kernel_launch(void* const* d_in, const int* in_sizes, int n_in,
                              void* d_out, int out_size, void* d_ws, size_t ws_size,
                              hipStream_t stream) {
  const float* x_in  = (const float*)d_in[0];
  const int* col_ids = (const int*)d_in[1];
  const int* row_ids = (const int*)d_in[2];
  const int* nbr_ids = (const int*)d_in[3];
  const float* g_attn = (const float*)d_in[11];
  const float* g_ffn  = (const float*)d_in[12];
  const float* g_out  = (const float*)d_in[13];

  char* ws = (char*)d_ws;
  float* x   = (float*)(ws);
  short* h   = (short*)(ws + (size_t)(8u  << 20));
  short* qkv = (short*)(ws + (size_t)(12u << 20));
  short* vt  = (short*)(ws + (size_t)(24u << 20));
  short* ob  = (short*)(ws + (size_t)(28u << 20));
  short* f   = (short*)(ws + (size_t)(12u << 20));  // ffn phase, overlaps qkv/vt/ob
  short* fa  = (short*)(ws + (size_t)(44u << 20));
  short* wqkv = (short*)(ws + (size_t)(60u  << 20));  // [16][1536][512]
  short* wob  = (short*)(ws + (size_t)(84u  << 20));  // [16][512][512]
  short* w13  = (short*)(ws + (size_t)(92u  << 20));  // [4][4096][512]
  short* w2b  = (short*)(ws + (size_t)(108u << 20));  // [4][512][2048]

  const int N4 = 1048576;  // 4M elems / 4 per weight array
  cvt_place<<<4096, 256, 0, stream>>>((const f32x4*)d_in[4], (s16x4*)wqkv, N4, 16, 196608, 0, 0.125f);
  cvt_place<<<4096, 256, 0, stream>>>((const f32x4*)d_in[5], (s16x4*)wqkv, N4, 16, 196608, 65536, 1.0f);
  cvt_place<<<4096, 256, 0, stream>>>((const f32x4*)d_in[6], (s16x4*)wqkv, N4, 16, 196608, 131072, 1.0f);
  cvt_place<<<4096, 256, 0, stream>>>((const f32x4*)d_in[7], (s16x4*)wob,  N4, 20, 0, 0, 1.0f);
  cvt_place<<<4096, 256, 0, stream>>>((const f32x4*)d_in[8], (s16x4*)w13,  N4, 18, 524288, 0, 1.0f);
  cvt_place<<<4096, 256, 0, stream>>>((const f32x4*)d_in[9], (s16x4*)w13,  N4, 18, 524288, 262144, 1.0f);
  cvt_place<<<4096, 256, 0, stream>>>((const f32x4*)d_in[10], (s16x4*)w2b, N4, 20, 0, 0, 1.0f);

  hipMemcpyAsync(x, x_in, (size_t)MTOT * DM * 4, hipMemcpyDeviceToDevice, stream);

  const int* idsarr[4] = {col_ids, row_ids, nbr_ids, nullptr};

  for (int l = 0; l < 4; l++) {
    for (int r = 0; r < 4; r++) {
      rmsnorm_kernel<false><<<1024, 256, 0, stream>>>(x, g_attn + (size_t)(l * 4 + r) * DM, (void*)h);
      size_t woff = (size_t)(l * 4 + r) * 1536 * DM;
      gemm_bt<4, 2, 2><<<dim3(32, 24), 256, 0, stream>>>(h, wqkv + woff, qkv, nullptr, vt, 1536, DM);
      attn_kernel<<<dim3(32, 16), 256, 0, stream>>>(qkv, vt, idsarr[r], ob);
      gemm_bt<2, 2, 1><<<dim3(64, 8), 256, 0, stream>>>(ob, wob + (size_t)(l * 4 + r) * DM * DM,
                                                        nullptr, x, nullptr, DM, DM);
    }
    rmsnorm_kernel<false><<<1024, 256, 0, stream>>>(x, g_ffn + (size_t)l * DM, (void*)h);
    gemm_bt<4, 4, 0><<<dim3(32, 32), 256, 0, stream>>>(h, w13 + (size_t)l * 4096 * DM, f, nullptr, nullptr, 4096, DM);
    swiglu_kernel<<<4096, 256, 0, stream>>>(f, fa, MTOT * 2048 / 8);
    gemm_bt<2, 2, 1><<<dim3(64, 8), 256, 0, stream>>>(fa, w2b + (size_t)l * DM * 2048, nullptr, x, nullptr, DM, 2048);
  }
  rmsnorm_kernel<true><<<1024, 256, 0, stream>>>(x, g_out, d_out);
}

// Round 4
// 1237.444 us; speedup vs baseline: 1.6821x; 1.0129x over previous
//
#include <hip/hip_runtime.h>
#include <hip/hip_bf16.h>

// RelationalTransformer forward on MI355X (gfx950). Round 3.
// bf16 MFMA everywhere; fp32 residual. Swapped-QK^T flash attention with
// in-register softmax in exp2 domain (log2e folded into Wq), defer-max,
// QBLK=128/KVBLK=128, and a permuted V global layout so PV B-fragments are
// single ds_read_b128. W1/W3 interleaved so the W13 GEMM epilogue emits
// silu(h1)*h3 directly (no swiglu pass).
// Workspace:
//   [0,8M)    x     fp32 [4096,512]
//   [8M,12M)  h     bf16 [4096,512]
//   [12M,24M) qkv   bf16 [4096,1536]   (q,k halves used; v written to vt)
//   [24M,28M) vt    bf16 [32bh][64d][1024s]  (s sub-granule-permuted)
//   [28M,32M) ob    bf16 [4096,512]
//   [44M,60M) fa    bf16 [4096,2048]
//   [60M,116M) weights: wqkv 24M | wo 8M | w13 16M (interleaved) | w2 8M

typedef __attribute__((ext_vector_type(4))) float f32x4;
typedef __attribute__((ext_vector_type(8))) short s16x8;
typedef __attribute__((ext_vector_type(4))) short s16x4;

#define SEQ 1024
#define DM 512
#define MTOT 4096
#define EPSV 1.1920929e-07f
#define LOG2E 1.44269504088896f

static __device__ __forceinline__ float b2f(short s) {
  unsigned u = ((unsigned)(unsigned short)s) << 16;
  return __builtin_bit_cast(float, u);
}
static __device__ __forceinline__ short f2b(float f) {
  unsigned u = __builtin_bit_cast(unsigned, f);
  u = (u + 0x7fffu + ((u >> 16) & 1u)) >> 16;  // RNE; inputs never NaN
  return (short)(unsigned short)u;
}

#define MFMA_BF16(a, b, c) __builtin_amdgcn_mfma_f32_16x16x32_bf16((a), (b), (c), 0, 0, 0)
#define GLLDS(gp, lp)                                                                        \
  __builtin_amdgcn_global_load_lds((const __attribute__((address_space(1))) unsigned*)(gp),  \
                                   (__attribute__((address_space(3))) unsigned*)(lp), 16, 0, 0)
#define GLLDS4(gp, lp)                                                                       \
  __builtin_amdgcn_global_load_lds((const __attribute__((address_space(1))) unsigned*)(gp),  \
                                   (__attribute__((address_space(3))) unsigned*)(lp), 4, 0, 0)

// ---------------- fp32 -> bf16 weight conversion with placement + scale ----------------
__global__ void cvt_place(const f32x4* __restrict__ src, s16x4* __restrict__ dst, int n4,
                          int shift, int stride4, int off4, float scale) {
  int i = blockIdx.x * 256 + threadIdx.x;
  if (i >= n4) return;
  f32x4 v = src[i];
  s16x4 o;
  o[0] = f2b(v[0] * scale); o[1] = f2b(v[1] * scale);
  o[2] = f2b(v[2] * scale); o[3] = f2b(v[3] * scale);
  int c = i >> shift, r = i & ((1 << shift) - 1);
  dst[(size_t)c * stride4 + off4 + r] = o;
}

// ---------------- W1/W3 -> interleaved packed rows (2n = W1 row n, 2n+1 = W3 row n) ----------------
__global__ void cvt_w13(const f32x4* __restrict__ src, s16x4* __restrict__ dst, int n4, int off) {
  int i = blockIdx.x * 256 + threadIdx.x;
  if (i >= n4) return;
  f32x4 v = src[i];
  s16x4 o;
  o[0] = f2b(v[0]); o[1] = f2b(v[1]); o[2] = f2b(v[2]); o[3] = f2b(v[3]);
  int srcrow = i >> 7, r = i & 127;          // 128 x 4-elem chunks per 512-row
  int l = srcrow >> 11, n = srcrow & 2047;
  int dstrow = l * 4096 + n * 2 + off;
  dst[(size_t)dstrow * 128 + r] = o;
}

// ---------------- RMSNorm: one wave per row ----------------
template<bool F32OUT>
__global__ void rmsnorm_kernel(const float* __restrict__ x, const float* __restrict__ g,
                               void* __restrict__ outp) {
  int row = blockIdx.x * 4 + (threadIdx.x >> 6);
  int lane = threadIdx.x & 63;
  const float* xr = x + (size_t)row * DM + lane * 8;
  f32x4 a = *(const f32x4*)xr;
  f32x4 b = *(const f32x4*)(xr + 4);
  float ss = a[0]*a[0]+a[1]*a[1]+a[2]*a[2]+a[3]*a[3]+b[0]*b[0]+b[1]*b[1]+b[2]*b[2]+b[3]*b[3];
#pragma unroll
  for (int m = 1; m < 64; m <<= 1) ss += __shfl_xor(ss, m, 64);
  float sc = rsqrtf(ss * (1.0f / DM) + EPSV);
  const float* gp = g + lane * 8;
  if (F32OUT) {
    float* o = (float*)outp + (size_t)row * DM + lane * 8;
    f32x4 o0, o1;
#pragma unroll
    for (int j = 0; j < 4; j++) { o0[j] = a[j] * sc * gp[j]; o1[j] = b[j] * sc * gp[4 + j]; }
    *(f32x4*)o = o0;
    *(f32x4*)(o + 4) = o1;
  } else {
    s16x8 o;
#pragma unroll
    for (int j = 0; j < 4; j++) { o[j] = f2b(a[j] * sc * gp[j]); o[4 + j] = f2b(b[j] * sc * gp[4 + j]); }
    *(s16x8*)((short*)outp + (size_t)row * DM + lane * 8) = o;
  }
}

// ---------------- GEMM: out[M,N] = A[M,K] @ W[N,K]^T ----------------
// FUSE 0: bf16 out. FUSE 1: fp32 += into outf. FUSE 2: qkv mode (cols>=1024 ->
// permuted-transposed V write to vtb). FUSE 3: interleaved W13 -> silu fusion,
// writes fa (stride N/2) via lane-pair shfl.
template<int AR, int AC, int FUSE>
__global__ __launch_bounds__(256) void gemm_bt(const short* __restrict__ A, const short* __restrict__ W,
                                               short* __restrict__ outb, float* __restrict__ outf,
                                               short* __restrict__ vtb, int N, int K) {
  constexpr int BM = AR * 32;
  constexpr int BN = AC * 32;
  __shared__ short As[BM * 32];
  __shared__ short Bs[BN * 32];
  const int tid = threadIdx.x;
  const int lane = tid & 63;
  const int w = tid >> 6;
  const int wr = w >> 1, wc = w & 1;
  const int m0 = blockIdx.x * BM, n0 = blockIdx.y * BN;
  f32x4 acc[AR][AC] = {};
  for (int k = 0; k < K; k += 32) {
    __syncthreads();
#pragma unroll
    for (int i = 0; i < BM / 64; i++) {
      int s = i * 256 + tid;
      int row = s >> 2, gl = s & 3, gd = gl ^ ((row >> 1) & 3);
      GLLDS(A + (size_t)(m0 + row) * K + k + gd * 8, (char*)As + (i * 256 + w * 64) * 16);
    }
#pragma unroll
    for (int i = 0; i < BN / 64; i++) {
      int s = i * 256 + tid;
      int row = s >> 2, gl = s & 3, gd = gl ^ ((row >> 1) & 3);
      GLLDS(W + (size_t)(n0 + row) * K + k + gd * 8, (char*)Bs + (i * 256 + w * 64) * 16);
    }
    __syncthreads();
    s16x8 af[AR], bf[AC];
#pragma unroll
    for (int i = 0; i < AR; i++) {
      int row = wr * AR * 16 + i * 16 + (lane & 15);
      int gl = (lane >> 4) ^ ((row >> 1) & 3);
      af[i] = *(const s16x8*)(As + row * 32 + gl * 8);
    }
#pragma unroll
    for (int j = 0; j < AC; j++) {
      int row = wc * AC * 16 + j * 16 + (lane & 15);
      int gl = (lane >> 4) ^ ((row >> 1) & 3);
      bf[j] = *(const s16x8*)(Bs + row * 32 + gl * 8);
    }
#pragma unroll
    for (int i = 0; i < AR; i++)
#pragma unroll
      for (int j = 0; j < AC; j++)
        acc[i][j] = MFMA_BF16(af[i], bf[j], acc[i][j]);
  }
#pragma unroll
  for (int i = 0; i < AR; i++) {
    int rbase = m0 + wr * AR * 16 + i * 16 + (lane >> 4) * 4;
#pragma unroll
    for (int j = 0; j < AC; j++) {
      int col = n0 + wc * AC * 16 + j * 16 + (lane & 15);
      if (FUSE == 2 && col >= 1024) {
        // V transpose with sub-granule permutation: o = q32*8+h*4+g -> p = q32*8+g*2+h
        int bbv = rbase >> 10, s = rbase & 1023;
        int c = col - 1024, hhv = c >> 6, d = c & 63;
        int o = (s & 63) >> 2;
        int gg = o & 3, h2 = (o >> 2) & 1, q32 = o >> 3;
        int pnew = q32 * 8 + gg * 2 + h2;
        s16x4 o4;
#pragma unroll
        for (int r = 0; r < 4; r++) o4[r] = f2b(acc[i][j][r]);
        *(s16x4*)(vtb + (((size_t)(bbv * 8 + hhv) * 64 + d) << 10) + (s & ~63) + pnew * 4) = o4;
      } else if (FUSE == 3) {
        // even col = h@W1[n], odd col = h@W3[n]; even lanes write silu(h1)*h3
#pragma unroll
        for (int r = 0; r < 4; r++) {
          float own = acc[i][j][r];
          float other = __shfl_xor(own, 1, 64);
          float sv = own / (1.0f + __expf(-own));
          if (!(lane & 1))
            outb[(size_t)(rbase + r) * (N >> 1) + (col >> 1)] = f2b(sv * other);
        }
      } else {
#pragma unroll
        for (int r = 0; r < 4; r++) {
          size_t idx = (size_t)(rbase + r) * N + col;
          if (FUSE == 1) outf[idx] += acc[i][j][r];
          else           outb[idx] = f2b(acc[i][j][r]);
        }
      }
    }
  }
}

// ---------------- Flash attention: 8 waves x 16 q rows, KVBLK=128, exp2 softmax ----------------
__global__ __launch_bounds__(512) void attn_kernel(const short* __restrict__ qkv, const short* __restrict__ vt,
                                                   const int* __restrict__ ids, short* __restrict__ Ob) {
  const int bh = blockIdx.x;
  const int bb = bh >> 3, hh = bh & 7;
  const int q0 = blockIdx.y * 128;
  const int tid = threadIdx.x, lane = tid & 63, w = tid >> 6;
  const int g = lane >> 4, qi = lane & 15;
  __shared__ short Kl[128 * 64];   // [k][d], XOR-swizzled 16B granules
  __shared__ short Vl[64 * 128];   // [d][k-permuted], XOR-swizzled 16B granules
  __shared__ int Kid[128];
  const short* kbase = qkv + 512 + hh * 64;
  const short* vbase = vt + (size_t)bh * 64 * SEQ;
  s16x8 qf0, qf1;
  {
    int qrow = q0 + w * 16 + qi;
    const short* qp = qkv + (size_t)(bb * SEQ + qrow) * 1536 + hh * 64 + g * 8;
    qf0 = *(const s16x8*)qp;
    qf1 = *(const s16x8*)(qp + 32);
  }
  int qid = 0;
  if (ids) qid = ids[bb * SEQ + q0 + w * 16 + qi];
  float m_ = -1e30f, l_ = 0.f;
  f32x4 oacc[4] = {};  // lane holds O[q'=g*4+r][d=dt*16+qi]

  for (int kt = 0; kt < SEQ; kt += 128) {
    __syncthreads();
#pragma unroll
    for (int i = 0; i < 2; i++) {
      int s = i * 512 + tid;
      int row = s >> 3, gl = s & 7, gd = gl ^ (row & 7);
      GLLDS(kbase + (size_t)(bb * SEQ + kt + row) * 1536 + gd * 8, (char*)Kl + (i * 512 + w * 64) * 16);
    }
#pragma unroll
    for (int i = 0; i < 2; i++) {
      int s = i * 512 + tid;
      int d = s >> 4, gl = s & 15, gd = gl ^ (d & 7);
      GLLDS(vbase + (size_t)d * SEQ + kt + gd * 8, (char*)Vl + (i * 512 + w * 64) * 16);
    }
    if (ids && w < 2) GLLDS4(ids + bb * SEQ + kt + w * 64 + lane, (char*)Kid + w * 256);
    __syncthreads();
    // QK^T swapped (log2 domain, log2e folded into Wq): p[kc][r] = S2[k=kt+kc*16+g*4+r][q]
    f32x4 sc[8];
#pragma unroll
    for (int kc = 0; kc < 8; kc++) {
      int krow = kc * 16 + qi;
      s16x8 kf0 = *(const s16x8*)(Kl + krow * 64 + ((g ^ (krow & 7)) * 8));
      s16x8 kf1 = *(const s16x8*)(Kl + krow * 64 + (((4 + g) ^ (krow & 7)) * 8));
      f32x4 s4 = {};
      s4 = MFMA_BF16(kf0, qf0, s4);
      s4 = MFMA_BF16(kf1, qf1, s4);
      sc[kc] = s4;
    }
    float p[8][4];
#pragma unroll
    for (int kc = 0; kc < 8; kc++)
#pragma unroll
      for (int r = 0; r < 4; r++) p[kc][r] = sc[kc][r];
    if (ids) {
#pragma unroll
      for (int kc = 0; kc < 8; kc++) {
        int4 kid4 = *(const int4*)(Kid + kc * 16 + g * 4);
        if (kid4.x != qid) p[kc][0] = -1e30f;
        if (kid4.y != qid) p[kc][1] = -1e30f;
        if (kid4.z != qid) p[kc][2] = -1e30f;
        if (kid4.w != qid) p[kc][3] = -1e30f;
      }
    }
    float mx = fmaxf(fmaxf(p[0][0], p[0][1]), fmaxf(p[0][2], p[0][3]));
#pragma unroll
    for (int kc = 1; kc < 8; kc++)
      mx = fmaxf(mx, fmaxf(fmaxf(p[kc][0], p[kc][1]), fmaxf(p[kc][2], p[kc][3])));
    mx = fmaxf(mx, __shfl_xor(mx, 16, 64));
    mx = fmaxf(mx, __shfl_xor(mx, 32, 64));
    // defer-max: only rescale when the running max grew by > 8 (p <= 2^8 safe in fp32)
    if (__any(mx > m_ + 8.f)) {
      float nm = fmaxf(m_, mx);
      float c = exp2f(m_ - nm);
      m_ = nm;
      l_ *= c;
#pragma unroll
      for (int r = 0; r < 4; r++) {
        float cr = __shfl(c, g * 4 + r, 16);
        oacc[0][r] *= cr; oacc[1][r] *= cr; oacc[2][r] *= cr; oacc[3][r] *= cr;
      }
    }
    float sum = 0.f;
#pragma unroll
    for (int kc = 0; kc < 8; kc++)
#pragma unroll
      for (int r = 0; r < 4; r++) {
        p[kc][r] = exp2f(p[kc][r] - m_);
        sum += p[kc][r];
      }
    sum += __shfl_xor(sum, 16, 64);
    sum += __shfl_xor(sum, 32, 64);
    l_ += sum;
    // PV per 64-k block: single b128 V fragments thanks to permuted vt layout
#pragma unroll
    for (int kk = 0; kk < 2; kk++) {
      s16x8 pa, pb;
#pragma unroll
      for (int r = 0; r < 4; r++) {
        pa[r] = f2b(p[kk * 4 + 0][r]); pa[4 + r] = f2b(p[kk * 4 + 1][r]);
        pb[r] = f2b(p[kk * 4 + 2][r]); pb[4 + r] = f2b(p[kk * 4 + 3][r]);
      }
#pragma unroll
      for (int dt = 0; dt < 4; dt++) {
        int dl = dt * 16 + qi;
        const short* vr = Vl + dl * 128;
        s16x8 vf0 = *(const s16x8*)(vr + (kk * 8 + (g ^ (dl & 7))) * 8);
        s16x8 vf1 = *(const s16x8*)(vr + (kk * 8 + ((4 + g) ^ (dl & 7))) * 8);
        oacc[dt] = MFMA_BF16(pa, vf0, oacc[dt]);
        oacc[dt] = MFMA_BF16(pb, vf1, oacc[dt]);
      }
    }
  }
  const size_t obase = (size_t)(bb * SEQ) * DM + hh * 64;
#pragma unroll
  for (int r = 0; r < 4; r++) {
    float lr = __shfl(l_, g * 4 + r, 16);
    float inv = 1.0f / lr;
    int q = q0 + w * 16 + g * 4 + r;
#pragma unroll
    for (int dt = 0; dt < 4; dt++)
      Ob[obase + (size_t)q * DM + dt * 16 + qi] = f2b(oacc[dt][r] * inv);
  }
}

// ---------------- host ----------------
extern "C" void kernel_launch(void* const* d_in, const int* in_sizes, int n_in,
                              void* d_out, int out_size, void* d_ws, size_t ws_size,
                              hipStream_t stream) {
  const float* x_in  = (const float*)d_in[0];
  const int* col_ids = (const int*)d_in[1];
  const int* row_ids = (const int*)d_in[2];
  const int* nbr_ids = (const int*)d_in[3];
  const float* g_attn = (const float*)d_in[11];
  const float* g_ffn  = (const float*)d_in[12];
  const float* g_out  = (const float*)d_in[13];

  char* ws = (char*)d_ws;
  float* x   = (float*)(ws);
  short* h   = (short*)(ws + (size_t)(8u  << 20));
  short* qkv = (short*)(ws + (size_t)(12u << 20));
  short* vt  = (short*)(ws + (size_t)(24u << 20));
  short* ob  = (short*)(ws + (size_t)(28u << 20));
  short* fa  = (short*)(ws + (size_t)(44u << 20));
  short* wqkv = (short*)(ws + (size_t)(60u  << 20));  // [16][1536][512]
  short* wob  = (short*)(ws + (size_t)(84u  << 20));  // [16][512][512]
  short* w13  = (short*)(ws + (size_t)(92u  << 20));  // [4][4096][512] interleaved
  short* w2b  = (short*)(ws + (size_t)(108u << 20));  // [4][512][2048]

  const int N4 = 1048576;  // 4M elems / 4 per weight array
  cvt_place<<<4096, 256, 0, stream>>>((const f32x4*)d_in[4], (s16x4*)wqkv, N4, 16, 196608, 0, 0.125f * LOG2E);
  cvt_place<<<4096, 256, 0, stream>>>((const f32x4*)d_in[5], (s16x4*)wqkv, N4, 16, 196608, 65536, 1.0f);
  cvt_place<<<4096, 256, 0, stream>>>((const f32x4*)d_in[6], (s16x4*)wqkv, N4, 16, 196608, 131072, 1.0f);
  cvt_place<<<4096, 256, 0, stream>>>((const f32x4*)d_in[7], (s16x4*)wob,  N4, 20, 0, 0, 1.0f);
  cvt_w13<<<4096, 256, 0, stream>>>((const f32x4*)d_in[8], (s16x4*)w13, N4, 0);
  cvt_w13<<<4096, 256, 0, stream>>>((const f32x4*)d_in[9], (s16x4*)w13, N4, 1);
  cvt_place<<<4096, 256, 0, stream>>>((const f32x4*)d_in[10], (s16x4*)w2b, N4, 20, 0, 0, 1.0f);

  hipMemcpyAsync(x, x_in, (size_t)MTOT * DM * 4, hipMemcpyDeviceToDevice, stream);

  const int* idsarr[4] = {col_ids, row_ids, nbr_ids, nullptr};

  for (int l = 0; l < 4; l++) {
    for (int r = 0; r < 4; r++) {
      rmsnorm_kernel<false><<<1024, 256, 0, stream>>>(x, g_attn + (size_t)(l * 4 + r) * DM, (void*)h);
      size_t woff = (size_t)(l * 4 + r) * 1536 * DM;
      gemm_bt<4, 2, 2><<<dim3(32, 24), 256, 0, stream>>>(h, wqkv + woff, qkv, nullptr, vt, 1536, DM);
      attn_kernel<<<dim3(32, 8), 512, 0, stream>>>(qkv, vt, idsarr[r], ob);
      gemm_bt<2, 2, 1><<<dim3(64, 8), 256, 0, stream>>>(ob, wob + (size_t)(l * 4 + r) * DM * DM,
                                                        nullptr, x, nullptr, DM, DM);
    }
    rmsnorm_kernel<false><<<1024, 256, 0, stream>>>(x, g_ffn + (size_t)l * DM, (void*)h);
    gemm_bt<4, 4, 3><<<dim3(32, 32), 256, 0, stream>>>(h, w13 + (size_t)l * 4096 * DM, fa, nullptr, nullptr, 4096, DM);
    gemm_bt<2, 2, 1><<<dim3(64, 8), 256, 0, stream>>>(fa, w2b + (size_t)l * DM * 2048, nullptr, x, nullptr, DM, 2048);
  }
  rmsnorm_kernel<true><<<1024, 256, 0, stream>>>(x, g_out, d_out);
}

// Round 5
// 1167.225 us; speedup vs baseline: 1.7833x; 1.0602x over previous
//
#include <hip/hip_runtime.h>
#include <hip/hip_bf16.h>

// RelationalTransformer forward on MI355X (gfx950). Round 4.
// R3 + 2-phase double-buffered staging in ALL GEMMs and the attention
// K/V staging loop: prefetch next K-tile via global_load_lds BEFORE the
// current tile's ds_read+MFMA, one barrier per K-step (T3 minimum recipe).
// Workspace layout unchanged from R3.

typedef __attribute__((ext_vector_type(4))) float f32x4;
typedef __attribute__((ext_vector_type(8))) short s16x8;
typedef __attribute__((ext_vector_type(4))) short s16x4;

#define SEQ 1024
#define DM 512
#define MTOT 4096
#define EPSV 1.1920929e-07f
#define LOG2E 1.44269504088896f

static __device__ __forceinline__ float b2f(short s) {
  unsigned u = ((unsigned)(unsigned short)s) << 16;
  return __builtin_bit_cast(float, u);
}
static __device__ __forceinline__ short f2b(float f) {
  unsigned u = __builtin_bit_cast(unsigned, f);
  u = (u + 0x7fffu + ((u >> 16) & 1u)) >> 16;  // RNE; inputs never NaN
  return (short)(unsigned short)u;
}

#define MFMA_BF16(a, b, c) __builtin_amdgcn_mfma_f32_16x16x32_bf16((a), (b), (c), 0, 0, 0)
#define GLLDS(gp, lp)                                                                        \
  __builtin_amdgcn_global_load_lds((const __attribute__((address_space(1))) unsigned*)(gp),  \
                                   (__attribute__((address_space(3))) unsigned*)(lp), 16, 0, 0)
#define GLLDS4(gp, lp)                                                                       \
  __builtin_amdgcn_global_load_lds((const __attribute__((address_space(1))) unsigned*)(gp),  \
                                   (__attribute__((address_space(3))) unsigned*)(lp), 4, 0, 0)

// ---------------- fp32 -> bf16 weight conversion with placement + scale ----------------
__global__ void cvt_place(const f32x4* __restrict__ src, s16x4* __restrict__ dst, int n4,
                          int shift, int stride4, int off4, float scale) {
  int i = blockIdx.x * 256 + threadIdx.x;
  if (i >= n4) return;
  f32x4 v = src[i];
  s16x4 o;
  o[0] = f2b(v[0] * scale); o[1] = f2b(v[1] * scale);
  o[2] = f2b(v[2] * scale); o[3] = f2b(v[3] * scale);
  int c = i >> shift, r = i & ((1 << shift) - 1);
  dst[(size_t)c * stride4 + off4 + r] = o;
}

// ---------------- W1/W3 -> interleaved packed rows (2n = W1 row n, 2n+1 = W3 row n) ----------------
__global__ void cvt_w13(const f32x4* __restrict__ src, s16x4* __restrict__ dst, int n4, int off) {
  int i = blockIdx.x * 256 + threadIdx.x;
  if (i >= n4) return;
  f32x4 v = src[i];
  s16x4 o;
  o[0] = f2b(v[0]); o[1] = f2b(v[1]); o[2] = f2b(v[2]); o[3] = f2b(v[3]);
  int srcrow = i >> 7, r = i & 127;
  int l = srcrow >> 11, n = srcrow & 2047;
  int dstrow = l * 4096 + n * 2 + off;
  dst[(size_t)dstrow * 128 + r] = o;
}

// ---------------- RMSNorm: one wave per row ----------------
template<bool F32OUT>
__global__ void rmsnorm_kernel(const float* __restrict__ x, const float* __restrict__ g,
                               void* __restrict__ outp) {
  int row = blockIdx.x * 4 + (threadIdx.x >> 6);
  int lane = threadIdx.x & 63;
  const float* xr = x + (size_t)row * DM + lane * 8;
  f32x4 a = *(const f32x4*)xr;
  f32x4 b = *(const f32x4*)(xr + 4);
  float ss = a[0]*a[0]+a[1]*a[1]+a[2]*a[2]+a[3]*a[3]+b[0]*b[0]+b[1]*b[1]+b[2]*b[2]+b[3]*b[3];
#pragma unroll
  for (int m = 1; m < 64; m <<= 1) ss += __shfl_xor(ss, m, 64);
  float sc = rsqrtf(ss * (1.0f / DM) + EPSV);
  const float* gp = g + lane * 8;
  if (F32OUT) {
    float* o = (float*)outp + (size_t)row * DM + lane * 8;
    f32x4 o0, o1;
#pragma unroll
    for (int j = 0; j < 4; j++) { o0[j] = a[j] * sc * gp[j]; o1[j] = b[j] * sc * gp[4 + j]; }
    *(f32x4*)o = o0;
    *(f32x4*)(o + 4) = o1;
  } else {
    s16x8 o;
#pragma unroll
    for (int j = 0; j < 4; j++) { o[j] = f2b(a[j] * sc * gp[j]); o[4 + j] = f2b(b[j] * sc * gp[4 + j]); }
    *(s16x8*)((short*)outp + (size_t)row * DM + lane * 8) = o;
  }
}

// ---------------- GEMM: out[M,N] = A[M,K] @ W[N,K]^T, 2-phase dbuf ----------------
// FUSE 0: bf16 out. FUSE 1: fp32 += outf. FUSE 2: qkv (cols>=1024 -> permuted V
// transpose to vtb). FUSE 3: interleaved W13 -> silu(h1)*h3 to outb (stride N/2).
template<int AR, int AC, int FUSE>
__global__ __launch_bounds__(256) void gemm_bt(const short* __restrict__ A, const short* __restrict__ W,
                                               short* __restrict__ outb, float* __restrict__ outf,
                                               short* __restrict__ vtb, int N, int K) {
  constexpr int BM = AR * 32;
  constexpr int BN = AC * 32;
  __shared__ short As[2][BM * 32];
  __shared__ short Bs[2][BN * 32];
  const int tid = threadIdx.x;
  const int lane = tid & 63;
  const int w = tid >> 6;
  const int wr = w >> 1, wc = w & 1;
  const int m0 = blockIdx.x * BM, n0 = blockIdx.y * BN;
  f32x4 acc[AR][AC] = {};

#define STAGE_GEMM(buf, kk)                                                                      \
  {                                                                                              \
    _Pragma("unroll")                                                                            \
    for (int i = 0; i < BM / 64; i++) {                                                          \
      int s = i * 256 + tid;                                                                     \
      int row = s >> 2, gl = s & 3, gd = gl ^ ((row >> 1) & 3);                                  \
      GLLDS(A + (size_t)(m0 + row) * K + (kk) + gd * 8, (char*)As[buf] + (i * 256 + w * 64) * 16);\
    }                                                                                            \
    _Pragma("unroll")                                                                            \
    for (int i = 0; i < BN / 64; i++) {                                                          \
      int s = i * 256 + tid;                                                                     \
      int row = s >> 2, gl = s & 3, gd = gl ^ ((row >> 1) & 3);                                  \
      GLLDS(W + (size_t)(n0 + row) * K + (kk) + gd * 8, (char*)Bs[buf] + (i * 256 + w * 64) * 16);\
    }                                                                                            \
  }

  STAGE_GEMM(0, 0);
  __syncthreads();
  int cur = 0;
  const int nt = K >> 5;
  for (int t = 0; t < nt; ++t) {
    if (t + 1 < nt) STAGE_GEMM(cur ^ 1, (t + 1) * 32);
    s16x8 af[AR], bf[AC];
#pragma unroll
    for (int i = 0; i < AR; i++) {
      int row = wr * AR * 16 + i * 16 + (lane & 15);
      int gl = (lane >> 4) ^ ((row >> 1) & 3);
      af[i] = *(const s16x8*)(As[cur] + row * 32 + gl * 8);
    }
#pragma unroll
    for (int j = 0; j < AC; j++) {
      int row = wc * AC * 16 + j * 16 + (lane & 15);
      int gl = (lane >> 4) ^ ((row >> 1) & 3);
      bf[j] = *(const s16x8*)(Bs[cur] + row * 32 + gl * 8);
    }
#pragma unroll
    for (int i = 0; i < AR; i++)
#pragma unroll
      for (int j = 0; j < AC; j++)
        acc[i][j] = MFMA_BF16(af[i], bf[j], acc[i][j]);
    __syncthreads();  // drains prefetch vmcnt; all reads of As[cur] done
    cur ^= 1;
  }
#undef STAGE_GEMM

#pragma unroll
  for (int i = 0; i < AR; i++) {
    int rbase = m0 + wr * AR * 16 + i * 16 + (lane >> 4) * 4;
#pragma unroll
    for (int j = 0; j < AC; j++) {
      int col = n0 + wc * AC * 16 + j * 16 + (lane & 15);
      if (FUSE == 2 && col >= 1024) {
        // V transpose with sub-granule permutation: o = q32*8+h*4+g -> p = q32*8+g*2+h
        int bbv = rbase >> 10, s = rbase & 1023;
        int c = col - 1024, hhv = c >> 6, d = c & 63;
        int o = (s & 63) >> 2;
        int gg = o & 3, h2 = (o >> 2) & 1, q32 = o >> 3;
        int pnew = q32 * 8 + gg * 2 + h2;
        s16x4 o4;
#pragma unroll
        for (int r = 0; r < 4; r++) o4[r] = f2b(acc[i][j][r]);
        *(s16x4*)(vtb + (((size_t)(bbv * 8 + hhv) * 64 + d) << 10) + (s & ~63) + pnew * 4) = o4;
      } else if (FUSE == 3) {
#pragma unroll
        for (int r = 0; r < 4; r++) {
          float own = acc[i][j][r];
          float other = __shfl_xor(own, 1, 64);
          float sv = own / (1.0f + __expf(-own));
          if (!(lane & 1))
            outb[(size_t)(rbase + r) * (N >> 1) + (col >> 1)] = f2b(sv * other);
        }
      } else {
#pragma unroll
        for (int r = 0; r < 4; r++) {
          size_t idx = (size_t)(rbase + r) * N + col;
          if (FUSE == 1) outf[idx] += acc[i][j][r];
          else           outb[idx] = f2b(acc[i][j][r]);
        }
      }
    }
  }
}

// ---------------- Flash attention: 8 waves x 16 q rows, KVBLK=128, 2-phase dbuf ----------------
__global__ __launch_bounds__(512) void attn_kernel(const short* __restrict__ qkv, const short* __restrict__ vt,
                                                   const int* __restrict__ ids, short* __restrict__ Ob) {
  const int bh = blockIdx.x;
  const int bb = bh >> 3, hh = bh & 7;
  const int q0 = blockIdx.y * 128;
  const int tid = threadIdx.x, lane = tid & 63, w = tid >> 6;
  const int g = lane >> 4, qi = lane & 15;
  __shared__ short Kl[2][128 * 64];   // [k][d], XOR-swizzled 16B granules
  __shared__ short Vl[2][64 * 128];   // [d][k-permuted], XOR-swizzled
  __shared__ int Kid[2][128];
  const short* kbase = qkv + 512 + hh * 64;
  const short* vbase = vt + (size_t)bh * 64 * SEQ;
  s16x8 qf0, qf1;
  {
    int qrow = q0 + w * 16 + qi;
    const short* qp = qkv + (size_t)(bb * SEQ + qrow) * 1536 + hh * 64 + g * 8;
    qf0 = *(const s16x8*)qp;
    qf1 = *(const s16x8*)(qp + 32);
  }
  int qid = 0;
  if (ids) qid = ids[bb * SEQ + q0 + w * 16 + qi];
  float m_ = -1e30f, l_ = 0.f;
  f32x4 oacc[4] = {};  // lane holds O[q'=g*4+r][d=dt*16+qi]

#define STAGE_ATTN(buf, ktt)                                                                     \
  {                                                                                              \
    _Pragma("unroll")                                                                            \
    for (int i = 0; i < 2; i++) {                                                                \
      int s = i * 512 + tid;                                                                     \
      int row = s >> 3, gl = s & 7, gd = gl ^ (row & 7);                                         \
      GLLDS(kbase + (size_t)(bb * SEQ + (ktt) + row) * 1536 + gd * 8,                            \
            (char*)Kl[buf] + (i * 512 + w * 64) * 16);                                           \
    }                                                                                            \
    _Pragma("unroll")                                                                            \
    for (int i = 0; i < 2; i++) {                                                                \
      int s = i * 512 + tid;                                                                     \
      int d = s >> 4, gl = s & 15, gd = gl ^ (d & 7);                                            \
      GLLDS(vbase + (size_t)d * SEQ + (ktt) + gd * 8, (char*)Vl[buf] + (i * 512 + w * 64) * 16); \
    }                                                                                            \
    if (ids && w < 2) GLLDS4(ids + bb * SEQ + (ktt) + w * 64 + lane, (char*)Kid[buf] + w * 256); \
  }

  STAGE_ATTN(0, 0);
  __syncthreads();
  int cur = 0;
  for (int kt = 0; kt < SEQ; kt += 128) {
    if (kt + 128 < SEQ) STAGE_ATTN(cur ^ 1, kt + 128);
    // QK^T swapped (log2 domain, log2e folded into Wq)
    f32x4 sc[8];
#pragma unroll
    for (int kc = 0; kc < 8; kc++) {
      int krow = kc * 16 + qi;
      s16x8 kf0 = *(const s16x8*)(Kl[cur] + krow * 64 + ((g ^ (krow & 7)) * 8));
      s16x8 kf1 = *(const s16x8*)(Kl[cur] + krow * 64 + (((4 + g) ^ (krow & 7)) * 8));
      f32x4 s4 = {};
      s4 = MFMA_BF16(kf0, qf0, s4);
      s4 = MFMA_BF16(kf1, qf1, s4);
      sc[kc] = s4;
    }
    float p[8][4];
#pragma unroll
    for (int kc = 0; kc < 8; kc++)
#pragma unroll
      for (int r = 0; r < 4; r++) p[kc][r] = sc[kc][r];
    if (ids) {
#pragma unroll
      for (int kc = 0; kc < 8; kc++) {
        int4 kid4 = *(const int4*)(Kid[cur] + kc * 16 + g * 4);
        if (kid4.x != qid) p[kc][0] = -1e30f;
        if (kid4.y != qid) p[kc][1] = -1e30f;
        if (kid4.z != qid) p[kc][2] = -1e30f;
        if (kid4.w != qid) p[kc][3] = -1e30f;
      }
    }
    float mx = fmaxf(fmaxf(p[0][0], p[0][1]), fmaxf(p[0][2], p[0][3]));
#pragma unroll
    for (int kc = 1; kc < 8; kc++)
      mx = fmaxf(mx, fmaxf(fmaxf(p[kc][0], p[kc][1]), fmaxf(p[kc][2], p[kc][3])));
    mx = fmaxf(mx, __shfl_xor(mx, 16, 64));
    mx = fmaxf(mx, __shfl_xor(mx, 32, 64));
    if (__any(mx > m_ + 8.f)) {   // defer-max
      float nm = fmaxf(m_, mx);
      float c = exp2f(m_ - nm);
      m_ = nm;
      l_ *= c;
#pragma unroll
      for (int r = 0; r < 4; r++) {
        float cr = __shfl(c, g * 4 + r, 16);
        oacc[0][r] *= cr; oacc[1][r] *= cr; oacc[2][r] *= cr; oacc[3][r] *= cr;
      }
    }
    float sum = 0.f;
#pragma unroll
    for (int kc = 0; kc < 8; kc++)
#pragma unroll
      for (int r = 0; r < 4; r++) {
        p[kc][r] = exp2f(p[kc][r] - m_);
        sum += p[kc][r];
      }
    sum += __shfl_xor(sum, 16, 64);
    sum += __shfl_xor(sum, 32, 64);
    l_ += sum;
    // PV: single b128 V fragments thanks to permuted vt layout
#pragma unroll
    for (int kk = 0; kk < 2; kk++) {
      s16x8 pa, pb;
#pragma unroll
      for (int r = 0; r < 4; r++) {
        pa[r] = f2b(p[kk * 4 + 0][r]); pa[4 + r] = f2b(p[kk * 4 + 1][r]);
        pb[r] = f2b(p[kk * 4 + 2][r]); pb[4 + r] = f2b(p[kk * 4 + 3][r]);
      }
#pragma unroll
      for (int dt = 0; dt < 4; dt++) {
        int dl = dt * 16 + qi;
        const short* vr = Vl[cur] + dl * 128;
        s16x8 vf0 = *(const s16x8*)(vr + (kk * 8 + (g ^ (dl & 7))) * 8);
        s16x8 vf1 = *(const s16x8*)(vr + (kk * 8 + ((4 + g) ^ (dl & 7))) * 8);
        oacc[dt] = MFMA_BF16(pa, vf0, oacc[dt]);
        oacc[dt] = MFMA_BF16(pb, vf1, oacc[dt]);
      }
    }
    __syncthreads();  // drains prefetch; all reads of [cur] done
    cur ^= 1;
  }
#undef STAGE_ATTN
  const size_t obase = (size_t)(bb * SEQ) * DM + hh * 64;
#pragma unroll
  for (int r = 0; r < 4; r++) {
    float lr = __shfl(l_, g * 4 + r, 16);
    float inv = 1.0f / lr;
    int q = q0 + w * 16 + g * 4 + r;
#pragma unroll
    for (int dt = 0; dt < 4; dt++)
      Ob[obase + (size_t)q * DM + dt * 16 + qi] = f2b(oacc[dt][r] * inv);
  }
}

// ---------------- host ----------------
extern "C" void kernel_launch(void* const* d_in, const int* in_sizes, int n_in,
                              void* d_out, int out_size, void* d_ws, size_t ws_size,
                              hipStream_t stream) {
  const float* x_in  = (const float*)d_in[0];
  const int* col_ids = (const int*)d_in[1];
  const int* row_ids = (const int*)d_in[2];
  const int* nbr_ids = (const int*)d_in[3];
  const float* g_attn = (const float*)d_in[11];
  const float* g_ffn  = (const float*)d_in[12];
  const float* g_out  = (const float*)d_in[13];

  char* ws = (char*)d_ws;
  float* x   = (float*)(ws);
  short* h   = (short*)(ws + (size_t)(8u  << 20));
  short* qkv = (short*)(ws + (size_t)(12u << 20));
  short* vt  = (short*)(ws + (size_t)(24u << 20));
  short* ob  = (short*)(ws + (size_t)(28u << 20));
  short* fa  = (short*)(ws + (size_t)(44u << 20));
  short* wqkv = (short*)(ws + (size_t)(60u  << 20));  // [16][1536][512]
  short* wob  = (short*)(ws + (size_t)(84u  << 20));  // [16][512][512]
  short* w13  = (short*)(ws + (size_t)(92u  << 20));  // [4][4096][512] interleaved
  short* w2b  = (short*)(ws + (size_t)(108u << 20));  // [4][512][2048]

  const int N4 = 1048576;
  cvt_place<<<4096, 256, 0, stream>>>((const f32x4*)d_in[4], (s16x4*)wqkv, N4, 16, 196608, 0, 0.125f * LOG2E);
  cvt_place<<<4096, 256, 0, stream>>>((const f32x4*)d_in[5], (s16x4*)wqkv, N4, 16, 196608, 65536, 1.0f);
  cvt_place<<<4096, 256, 0, stream>>>((const f32x4*)d_in[6], (s16x4*)wqkv, N4, 16, 196608, 131072, 1.0f);
  cvt_place<<<4096, 256, 0, stream>>>((const f32x4*)d_in[7], (s16x4*)wob,  N4, 20, 0, 0, 1.0f);
  cvt_w13<<<4096, 256, 0, stream>>>((const f32x4*)d_in[8], (s16x4*)w13, N4, 0);
  cvt_w13<<<4096, 256, 0, stream>>>((const f32x4*)d_in[9], (s16x4*)w13, N4, 1);
  cvt_place<<<4096, 256, 0, stream>>>((const f32x4*)d_in[10], (s16x4*)w2b, N4, 20, 0, 0, 1.0f);

  hipMemcpyAsync(x, x_in, (size_t)MTOT * DM * 4, hipMemcpyDeviceToDevice, stream);

  const int* idsarr[4] = {col_ids, row_ids, nbr_ids, nullptr};

  for (int l = 0; l < 4; l++) {
    for (int r = 0; r < 4; r++) {
      rmsnorm_kernel<false><<<1024, 256, 0, stream>>>(x, g_attn + (size_t)(l * 4 + r) * DM, (void*)h);
      size_t woff = (size_t)(l * 4 + r) * 1536 * DM;
      gemm_bt<4, 2, 2><<<dim3(32, 24), 256, 0, stream>>>(h, wqkv + woff, qkv, nullptr, vt, 1536, DM);
      attn_kernel<<<dim3(32, 8), 512, 0, stream>>>(qkv, vt, idsarr[r], ob);
      gemm_bt<2, 2, 1><<<dim3(64, 8), 256, 0, stream>>>(ob, wob + (size_t)(l * 4 + r) * DM * DM,
                                                        nullptr, x, nullptr, DM, DM);
    }
    rmsnorm_kernel<false><<<1024, 256, 0, stream>>>(x, g_ffn + (size_t)l * DM, (void*)h);
    gemm_bt<4, 4, 3><<<dim3(32, 32), 256, 0, stream>>>(h, w13 + (size_t)l * 4096 * DM, fa, nullptr, nullptr, 4096, DM);
    gemm_bt<2, 2, 1><<<dim3(64, 8), 256, 0, stream>>>(fa, w2b + (size_t)l * DM * 2048, nullptr, x, nullptr, DM, 2048);
  }
  rmsnorm_kernel<true><<<1024, 256, 0, stream>>>(x, g_out, d_out);
}